// Round 7
// baseline (5140.286 us; speedup 1.0000x reference)
//
#include <hip/hip_runtime.h>
#include <hip/hip_bf16.h>

// GNN_84043920048593: hetero SAGEConv (title/label bipartite + label-label)
// Evidence from npz sizes: float inputs are f32, output buffer is f32.
// Input dtype still probed at runtime (cheap insurance); output stored f32.

typedef unsigned short u16;
typedef unsigned int   u32;

__device__ __forceinline__ float bf2f(u16 u) {
    union { u32 i; float f; } v; v.i = (u32)u << 16; return v.f;
}
// dual-dtype scalar load
__device__ __forceinline__ float ldf(const void* p, size_t i, int isbf) {
    return isbf ? bf2f(((const u16*)p)[i]) : ((const float*)p)[i];
}

// ---------- dtype probe: flag=1 if x looks like packed bf16, 0 if f32 -------
__global__ void probe_kernel(const u32* __restrict__ x, int* __restrict__ flag)
{
    __shared__ int sh[256];
    int hits = 0;
    for (int i = threadIdx.x; i < 4096; i += 256) {
        u32 lo = x[i] & 0xFFFFu;
        u32 e  = (lo >> 7) & 0xFFu;
        if (lo == 0u || (e >= 96u && e <= 142u)) hits++;
    }
    sh[threadIdx.x] = hits;
    __syncthreads();
    for (int s = 128; s > 0; s >>= 1) {
        if (threadIdx.x < s) sh[threadIdx.x] += sh[threadIdx.x + s];
        __syncthreads();
    }
    if (threadIdx.x == 0) *flag = (sh[0] > 2048) ? 1 : 0;
}

// ---------- sentinel: ws_size too small -> absmax ~999 tells us why ---------
__global__ void sentinel_kernel(float* out, int n) {
    int i = blockIdx.x * 256 + threadIdx.x;
    if (i < n) out[i] = 999.0f;
}

// ---------- edge aggregation: agg[dst] += x_src[src], cnt[dst]++ ------------
// 16 lanes per edge; each lane covers 4 features.
__global__ void __launch_bounds__(256)
edge_agg_kernel(const void* __restrict__ xsrc,
                const int* __restrict__ src,
                const int* __restrict__ dst,
                const int* __restrict__ remap,      // label_node_id or nullptr
                float* __restrict__ agg,
                int* __restrict__ cnt,
                int nedges,
                const int* __restrict__ flag)
{
    long long t = (long long)blockIdx.x * 256 + threadIdx.x;
    int e = (int)(t >> 4);
    if (e >= nedges) return;
    int lane = (int)(t & 15);
    int s = src[e];
    if (remap) s = remap[s];
    int d = dst[e];
    float4 v;
    if (*flag) {
        ushort4 w = ((const ushort4*)xsrc)[(size_t)s * 16 + lane];
        v = make_float4(bf2f(w.x), bf2f(w.y), bf2f(w.z), bf2f(w.w));
    } else {
        v = ((const float4*)xsrc)[(size_t)s * 16 + lane];
    }
    float* a = agg + (size_t)d * 64 + lane * 4;
    atomicAdd(a + 0, v.x);
    atomicAdd(a + 1, v.y);
    atomicAdd(a + 2, v.z);
    atomicAdd(a + 3, v.w);
    if (lane == 0) atomicAdd(cnt + d, 1);
}

// ---------- label output: relu(agg_tl@Wl_tl^T + agg_ll@Wl_ll^T
//            + x_label@(Wr_tl+Wr_ll)^T + bl_tl + bl_ll) ---------------------
__global__ void __launch_bounds__(256)
label_out_kernel(const float* __restrict__ agg_tl,
                 const float* __restrict__ agg_ll,
                 const int* __restrict__ cnt_tl,
                 const int* __restrict__ cnt_ll,
                 const void* __restrict__ label_embed,
                 const int* __restrict__ label_node_id,
                 const void* __restrict__ Wl_tl, const void* __restrict__ bl_tl,
                 const void* __restrict__ Wr_tl,
                 const void* __restrict__ Wl_ll, const void* __restrict__ bl_ll,
                 const void* __restrict__ Wr_ll,
                 float* __restrict__ out, int n_labels,
                 const int* __restrict__ flag)
{
    int isbf = *flag;
    __shared__ float wtl[64 * 64];  // wtl[k*64+j] = Wl_tl[j][k]
    __shared__ float wll[64 * 64];
    __shared__ float wr [64 * 64];  // Wr_tl[j][k] + Wr_ll[j][k]
    for (int idx = threadIdx.x; idx < 4096; idx += 256) {
        int k = idx >> 6, j = idx & 63;
        wtl[idx] = ldf(Wl_tl, j * 64 + k, isbf);
        wll[idx] = ldf(Wl_ll, j * 64 + k, isbf);
        wr [idx] = ldf(Wr_tl, j * 64 + k, isbf) + ldf(Wr_ll, j * 64 + k, isbf);
    }
    __syncthreads();

    int wave = threadIdx.x >> 6;
    int lane = threadIdx.x & 63;
    int i = blockIdx.x * 4 + wave;
    if (i >= n_labels) return;

    int nid = label_node_id[i];
    float inv_tl = 1.0f / fmaxf((float)cnt_tl[i], 1.0f);
    float inv_ll = 1.0f / fmaxf((float)cnt_ll[i], 1.0f);
    float a_tl = agg_tl[(size_t)i * 64 + lane] * inv_tl;
    float a_ll = agg_ll[(size_t)i * 64 + lane] * inv_ll;
    float xr   = ldf(label_embed, (size_t)nid * 64 + lane, isbf);
    float acc  = ldf(bl_tl, lane, isbf) + ldf(bl_ll, lane, isbf);
    #pragma unroll 8
    for (int k = 0; k < 64; ++k) {
        float btl = __shfl(a_tl, k);
        float bll = __shfl(a_ll, k);
        float bxr = __shfl(xr, k);
        acc += btl * wtl[k * 64 + lane]
             + bll * wll[k * 64 + lane]
             + bxr * wr [k * 64 + lane];
    }
    out[(size_t)i * 64 + lane] = fmaxf(acc, 0.0f);
}

// ---------- title output: relu(agg_lt@Wl_tl^T + bl_tl + title_x@Wr_tl^T) ----
__global__ void __launch_bounds__(256)
title_out_kernel(const float* __restrict__ agg_lt,
                 const int* __restrict__ cnt_lt,
                 const void* __restrict__ title_x,
                 const void* __restrict__ Wl_tl, const void* __restrict__ bl_tl,
                 const void* __restrict__ Wr_tl,
                 float* __restrict__ out, int n_titles,
                 const int* __restrict__ flag)
{
    int isbf = *flag;
    __shared__ float wl[64 * 64];
    __shared__ float wr[64 * 64];
    for (int idx = threadIdx.x; idx < 4096; idx += 256) {
        int k = idx >> 6, j = idx & 63;
        wl[idx] = ldf(Wl_tl, j * 64 + k, isbf);
        wr[idx] = ldf(Wr_tl, j * 64 + k, isbf);
    }
    __syncthreads();

    int wave = threadIdx.x >> 6;
    int lane = threadIdx.x & 63;
    int i = blockIdx.x * 4 + wave;
    if (i >= n_titles) return;

    float inv = 1.0f / fmaxf((float)cnt_lt[i], 1.0f);
    float a   = agg_lt[(size_t)i * 64 + lane] * inv;
    float xr  = ldf(title_x, (size_t)i * 64 + lane, isbf);
    float acc = ldf(bl_tl, lane, isbf);
    #pragma unroll 8
    for (int k = 0; k < 64; ++k) {
        float ba = __shfl(a, k);
        float bx = __shfl(xr, k);
        acc += ba * wl[k * 64 + lane] + bx * wr[k * 64 + lane];
    }
    out[(size_t)i * 64 + lane] = fmaxf(acc, 0.0f);
}

extern "C" void kernel_launch(void* const* d_in, const int* in_sizes, int n_in,
                              void* d_out, int out_size, void* d_ws, size_t ws_size,
                              hipStream_t stream)
{
    const void* title_x   = d_in[0];
    const void* label_emb = d_in[1];
    const void* Wl_tl     = d_in[2];
    const void* bl_tl     = d_in[3];
    const void* Wr_tl     = d_in[4];
    const void* Wl_ll     = d_in[5];
    const void* bl_ll     = d_in[6];
    const void* Wr_ll     = d_in[7];
    const int* label_node_id = (const int*)d_in[8];
    const int* tl_src = (const int*)d_in[9];
    const int* tl_dst = (const int*)d_in[10];
    const int* lt_src = (const int*)d_in[11];
    const int* lt_dst = (const int*)d_in[12];
    const int* ll_src = (const int*)d_in[13];
    const int* ll_dst = (const int*)d_in[14];

    const int NT  = in_sizes[0] / 64;
    const int NL  = in_sizes[8];
    const int eTL = in_sizes[9];
    const int eLT = in_sizes[11];
    const int eLL = in_sizes[13];

    // Workspace overlay: phase A (label aggs) then phase B (title agg) reuse.
    size_t aggA    = (size_t)NL * 64 * 4;                    // 25.6 MB
    size_t regionA = 2 * aggA + 2 * (size_t)NL * 4;          // 52.0 MB
    size_t regionB = (size_t)NT * 64 * 4 + (size_t)NT * 4;   // 52.0 MB
    size_t big     = regionA > regionB ? regionA : regionB;
    size_t needed  = big + 256;

    float* out_label = (float*)d_out;
    float* out_title = out_label + (size_t)NL * 64;

    if (ws_size < needed) {  // diagnosable failure: absmax ~999
        sentinel_kernel<<<(out_size + 255) / 256, 256, 0, stream>>>((float*)d_out, out_size);
        return;
    }

    char* base = (char*)d_ws;
    float* agg_tl = (float*)base;
    float* agg_ll = (float*)(base + aggA);
    int*   cnt_tl = (int*)(base + 2 * aggA);
    int*   cnt_ll = (int*)(base + 2 * aggA + (size_t)NL * 4);
    float* agg_lt = (float*)base;                            // phase B overlay
    int*   cnt_lt = (int*)(base + (size_t)NT * 64 * 4);
    int*   flag   = (int*)(base + big);

    auto nblk = [](long long threads) { return (int)((threads + 255) / 256); };

    (void)hipMemsetAsync(d_ws, 0, big + 256, stream);
    probe_kernel<<<1, 256, 0, stream>>>((const u32*)title_x, flag);

    // phase A: label destination
    edge_agg_kernel<<<nblk((long long)eTL * 16), 256, 0, stream>>>(
        title_x, tl_src, tl_dst, nullptr, agg_tl, cnt_tl, eTL, flag);
    edge_agg_kernel<<<nblk((long long)eLL * 16), 256, 0, stream>>>(
        label_emb, ll_src, ll_dst, label_node_id, agg_ll, cnt_ll, eLL, flag);
    label_out_kernel<<<(NL + 3) / 4, 256, 0, stream>>>(
        agg_tl, agg_ll, cnt_tl, cnt_ll, label_emb, label_node_id,
        Wl_tl, bl_tl, Wr_tl, Wl_ll, bl_ll, Wr_ll, out_label, NL, flag);

    // phase B: title destination (reuses the same ws region; stream-ordered)
    (void)hipMemsetAsync(d_ws, 0, big, stream);
    edge_agg_kernel<<<nblk((long long)eLT * 16), 256, 0, stream>>>(
        label_emb, lt_src, lt_dst, label_node_id, agg_lt, cnt_lt, eLT, flag);
    title_out_kernel<<<(NT + 3) / 4, 256, 0, stream>>>(
        agg_lt, cnt_lt, title_x, Wl_tl, bl_tl, Wr_tl, out_title, NT, flag);
}

// Round 8
// 3147.864 us; speedup vs baseline: 1.6329x; 1.6329x over previous
//
#include <hip/hip_runtime.h>
#include <hip/hip_bf16.h>

// GNN_84043920048593: hetero SAGEConv. f32 I/O (confirmed round 7).
// R7 counters: edge atomic-scatter wrote 1.65GB/dispatch to HBM (line-RMW
// amplification, ~1030B/edge). This round: CSR counting-sort + gather-reduce,
// no f32 atomics.

typedef unsigned short u16;
typedef unsigned int   u32;

__device__ __forceinline__ float bf2f(u16 u) {
    union { u32 i; float f; } v; v.i = (u32)u << 16; return v.f;
}
__device__ __forceinline__ float ldf(const void* p, size_t i, int isbf) {
    return isbf ? bf2f(((const u16*)p)[i]) : ((const float*)p)[i];
}

// ---------- dtype probe (validated r7: returns 0 for f32) -------------------
__global__ void probe_kernel(const u32* __restrict__ x, int* __restrict__ flag)
{
    __shared__ int sh[256];
    int hits = 0;
    for (int i = threadIdx.x; i < 4096; i += 256) {
        u32 lo = x[i] & 0xFFFFu;
        u32 e  = (lo >> 7) & 0xFFu;
        if (lo == 0u || (e >= 96u && e <= 142u)) hits++;
    }
    sh[threadIdx.x] = hits;
    __syncthreads();
    for (int s = 128; s > 0; s >>= 1) {
        if (threadIdx.x < s) sh[threadIdx.x] += sh[threadIdx.x + s];
        __syncthreads();
    }
    if (threadIdx.x == 0) *flag = (sh[0] > 2048) ? 1 : 0;
}

__global__ void sentinel_kernel(float* out, int n) {
    int i = blockIdx.x * 256 + threadIdx.x;
    if (i < n) out[i] = 999.0f;
}

// ---------- CSR build: histogram -> scan -> scatter -------------------------
__global__ void __launch_bounds__(256)
hist_kernel(const int* __restrict__ dst, int* __restrict__ cnt, int n) {
    int e = blockIdx.x * 256 + threadIdx.x;
    if (e < n) atomicAdd(cnt + dst[e], 1);
}

// single-WG blocked scan: cnt[] -> rp[] (exclusive starts) and cur[] (copy)
__global__ void __launch_bounds__(1024)
scan_kernel(const int* __restrict__ cnt, int* __restrict__ rp,
            int* __restrict__ cur, int n) {
    __shared__ int part[1024];
    int t = threadIdx.x;
    int C = (n + 1023) / 1024;
    int lo = t * C, hi = min(n, lo + C);
    int sum = 0;
    for (int j = lo; j < hi; ++j) sum += cnt[j];
    part[t] = sum;
    __syncthreads();
    for (int off = 1; off < 1024; off <<= 1) {
        int v = (t >= off) ? part[t - off] : 0;
        __syncthreads();
        part[t] += v;
        __syncthreads();
    }
    int running = part[t] - sum;            // exclusive base of my chunk
    for (int j = lo; j < hi; ++j) {
        int c = cnt[j];
        rp[j] = running; cur[j] = running;
        running += c;
    }
}

__global__ void __launch_bounds__(256)
scatter_kernel(const int* __restrict__ src, const int* __restrict__ dst,
               const int* __restrict__ remap,
               int* __restrict__ cur, int* __restrict__ bucket, int n) {
    int e = blockIdx.x * 256 + threadIdx.x;
    if (e >= n) return;
    int s = src[e];
    if (remap) s = remap[s];
    int pos = atomicAdd(cur + dst[e], 1);
    bucket[pos] = s;
}

// ---------- gather-reduce: agg[i] = mean of x[bucket[rp[i]..rp[i]+cnt[i])] --
// one wave per dst node; lane = feature.
__global__ void __launch_bounds__(256)
gather_mean_kernel(const void* __restrict__ x,
                   const int* __restrict__ rp,
                   const int* __restrict__ cnt,
                   const int* __restrict__ bucket,
                   float* __restrict__ agg,
                   int n_dst,
                   const int* __restrict__ flag)
{
    int isbf = *flag;
    int wave = threadIdx.x >> 6, lane = threadIdx.x & 63;
    int i = blockIdx.x * 4 + wave;
    if (i >= n_dst) return;
    int st = rp[i], deg = cnt[i];
    float acc = 0.0f;
    int j = 0;
    for (; j + 1 < deg; j += 2) {
        int s0 = bucket[st + j], s1 = bucket[st + j + 1];
        float v0 = ldf(x, (size_t)s0 * 64 + lane, isbf);
        float v1 = ldf(x, (size_t)s1 * 64 + lane, isbf);
        acc += v0 + v1;
    }
    if (j < deg)
        acc += ldf(x, (size_t)bucket[st + j] * 64 + lane, isbf);
    agg[(size_t)i * 64 + lane] = acc / fmaxf((float)deg, 1.0f);
}

// ---------- label output (agg already meaned) -------------------------------
__global__ void __launch_bounds__(256)
label_out_kernel(const float* __restrict__ agg_tl,
                 const float* __restrict__ agg_ll,
                 const void* __restrict__ label_embed,
                 const int* __restrict__ label_node_id,
                 const void* __restrict__ Wl_tl, const void* __restrict__ bl_tl,
                 const void* __restrict__ Wr_tl,
                 const void* __restrict__ Wl_ll, const void* __restrict__ bl_ll,
                 const void* __restrict__ Wr_ll,
                 float* __restrict__ out, int n_labels,
                 const int* __restrict__ flag)
{
    int isbf = *flag;
    __shared__ float wtl[64 * 64];  // wtl[k*64+j] = Wl_tl[j][k]
    __shared__ float wll[64 * 64];
    __shared__ float wr [64 * 64];  // Wr_tl + Wr_ll, transposed
    for (int idx = threadIdx.x; idx < 4096; idx += 256) {
        int k = idx >> 6, j = idx & 63;
        wtl[idx] = ldf(Wl_tl, j * 64 + k, isbf);
        wll[idx] = ldf(Wl_ll, j * 64 + k, isbf);
        wr [idx] = ldf(Wr_tl, j * 64 + k, isbf) + ldf(Wr_ll, j * 64 + k, isbf);
    }
    __syncthreads();

    int wave = threadIdx.x >> 6;
    int lane = threadIdx.x & 63;
    int i = blockIdx.x * 4 + wave;
    if (i >= n_labels) return;

    int nid = label_node_id[i];
    float a_tl = agg_tl[(size_t)i * 64 + lane];
    float a_ll = agg_ll[(size_t)i * 64 + lane];
    float xr   = ldf(label_embed, (size_t)nid * 64 + lane, isbf);
    float acc  = ldf(bl_tl, lane, isbf) + ldf(bl_ll, lane, isbf);
    #pragma unroll 8
    for (int k = 0; k < 64; ++k) {
        float btl = __shfl(a_tl, k);
        float bll = __shfl(a_ll, k);
        float bxr = __shfl(xr, k);
        acc += btl * wtl[k * 64 + lane]
             + bll * wll[k * 64 + lane]
             + bxr * wr [k * 64 + lane];
    }
    out[(size_t)i * 64 + lane] = fmaxf(acc, 0.0f);
}

// ---------- title output ----------------------------------------------------
__global__ void __launch_bounds__(256)
title_out_kernel(const float* __restrict__ agg_lt,
                 const void* __restrict__ title_x,
                 const void* __restrict__ Wl_tl, const void* __restrict__ bl_tl,
                 const void* __restrict__ Wr_tl,
                 float* __restrict__ out, int n_titles,
                 const int* __restrict__ flag)
{
    int isbf = *flag;
    __shared__ float wl[64 * 64];
    __shared__ float wr[64 * 64];
    for (int idx = threadIdx.x; idx < 4096; idx += 256) {
        int k = idx >> 6, j = idx & 63;
        wl[idx] = ldf(Wl_tl, j * 64 + k, isbf);
        wr[idx] = ldf(Wr_tl, j * 64 + k, isbf);
    }
    __syncthreads();

    int wave = threadIdx.x >> 6;
    int lane = threadIdx.x & 63;
    int i = blockIdx.x * 4 + wave;
    if (i >= n_titles) return;

    float a  = agg_lt[(size_t)i * 64 + lane];
    float xr = ldf(title_x, (size_t)i * 64 + lane, isbf);
    float acc = ldf(bl_tl, lane, isbf);
    #pragma unroll 8
    for (int k = 0; k < 64; ++k) {
        float ba = __shfl(a, k);
        float bx = __shfl(xr, k);
        acc += ba * wl[k * 64 + lane] + bx * wr[k * 64 + lane];
    }
    out[(size_t)i * 64 + lane] = fmaxf(acc, 0.0f);
}

extern "C" void kernel_launch(void* const* d_in, const int* in_sizes, int n_in,
                              void* d_out, int out_size, void* d_ws, size_t ws_size,
                              hipStream_t stream)
{
    const void* title_x   = d_in[0];
    const void* label_emb = d_in[1];
    const void* Wl_tl     = d_in[2];
    const void* bl_tl     = d_in[3];
    const void* Wr_tl     = d_in[4];
    const void* Wl_ll     = d_in[5];
    const void* bl_ll     = d_in[6];
    const void* Wr_ll     = d_in[7];
    const int* label_node_id = (const int*)d_in[8];
    const int* tl_src = (const int*)d_in[9];
    const int* tl_dst = (const int*)d_in[10];
    const int* lt_src = (const int*)d_in[11];
    const int* lt_dst = (const int*)d_in[12];
    const int* ll_src = (const int*)d_in[13];
    const int* ll_dst = (const int*)d_in[14];

    const int NT  = in_sizes[0] / 64;
    const int NL  = in_sizes[8];
    const int eTL = in_sizes[9];
    const int eLT = in_sizes[11];
    const int eLL = in_sizes[13];

    // ---- workspace overlay --------------------------------------------------
    // phase A (label): agg_tl, agg_ll, {cnt,rp,cur}x2, bucket_tl, bucket_ll
    // phase B (title): agg_lt, {cnt,rp,cur}, bucket_lt   (reuses same region)
    size_t szAgL = (size_t)NL * 64 * 4;       // one label agg: 25.6 MB
    size_t szAgT = (size_t)NT * 64 * 4;       // title agg:     51.2 MB
    size_t iNL   = (size_t)NL * 4;
    size_t iNT   = (size_t)NT * 4;

    size_t regionA = 2 * szAgL + 6 * iNL + ((size_t)eTL + eLL) * 4;  // ~63.2 MB
    size_t regionB = szAgT + 3 * iNT + (size_t)eLT * 4;              // ~60.0 MB
    size_t big     = regionA > regionB ? regionA : regionB;
    size_t needed  = big + 256;

    float* out_label = (float*)d_out;
    float* out_title = out_label + (size_t)NL * 64;

    if (ws_size < needed) {  // diagnosable failure: absmax ~999
        sentinel_kernel<<<(out_size + 255) / 256, 256, 0, stream>>>((float*)d_out, out_size);
        return;
    }

    char* base = (char*)d_ws;
    // phase A layout
    float* agg_tl = (float*)(base);
    float* agg_ll = (float*)(base + szAgL);
    int* cnt_tl = (int*)(base + 2 * szAgL);
    int* cnt_ll = (int*)(base + 2 * szAgL + iNL);
    int* rp_tl  = (int*)(base + 2 * szAgL + 2 * iNL);
    int* rp_ll  = (int*)(base + 2 * szAgL + 3 * iNL);
    int* cur_tl = (int*)(base + 2 * szAgL + 4 * iNL);
    int* cur_ll = (int*)(base + 2 * szAgL + 5 * iNL);
    int* bkt_tl = (int*)(base + 2 * szAgL + 6 * iNL);
    int* bkt_ll = bkt_tl + eTL;
    // phase B layout (overlays A)
    float* agg_lt = (float*)(base);
    int* cnt_lt = (int*)(base + szAgT);
    int* rp_lt  = (int*)(base + szAgT + iNT);
    int* cur_lt = (int*)(base + szAgT + 2 * iNT);
    int* bkt_lt = (int*)(base + szAgT + 3 * iNT);
    int* flag   = (int*)(base + big);

    auto eblk = [](int n) { return (n + 255) / 256; };

    probe_kernel<<<1, 256, 0, stream>>>((const u32*)title_x, flag);

    // ---- phase A: label destination ----------------------------------------
    (void)hipMemsetAsync(cnt_tl, 0, 2 * iNL, stream);   // cnt_tl + cnt_ll
    hist_kernel<<<eblk(eTL), 256, 0, stream>>>(tl_dst, cnt_tl, eTL);
    hist_kernel<<<eblk(eLL), 256, 0, stream>>>(ll_dst, cnt_ll, eLL);
    scan_kernel<<<1, 1024, 0, stream>>>(cnt_tl, rp_tl, cur_tl, NL);
    scan_kernel<<<1, 1024, 0, stream>>>(cnt_ll, rp_ll, cur_ll, NL);
    scatter_kernel<<<eblk(eTL), 256, 0, stream>>>(tl_src, tl_dst, nullptr, cur_tl, bkt_tl, eTL);
    scatter_kernel<<<eblk(eLL), 256, 0, stream>>>(ll_src, ll_dst, label_node_id, cur_ll, bkt_ll, eLL);
    gather_mean_kernel<<<(NL + 3) / 4, 256, 0, stream>>>(title_x,  rp_tl, cnt_tl, bkt_tl, agg_tl, NL, flag);
    gather_mean_kernel<<<(NL + 3) / 4, 256, 0, stream>>>(label_emb, rp_ll, cnt_ll, bkt_ll, agg_ll, NL, flag);
    label_out_kernel<<<(NL + 3) / 4, 256, 0, stream>>>(
        agg_tl, agg_ll, label_emb, label_node_id,
        Wl_tl, bl_tl, Wr_tl, Wl_ll, bl_ll, Wr_ll, out_label, NL, flag);

    // ---- phase B: title destination (stream-ordered reuse) -----------------
    (void)hipMemsetAsync(cnt_lt, 0, iNT, stream);
    hist_kernel<<<eblk(eLT), 256, 0, stream>>>(lt_dst, cnt_lt, eLT);
    scan_kernel<<<1, 1024, 0, stream>>>(cnt_lt, rp_lt, cur_lt, NT);
    scatter_kernel<<<eblk(eLT), 256, 0, stream>>>(lt_src, lt_dst, label_node_id, cur_lt, bkt_lt, eLT);
    gather_mean_kernel<<<(NT + 3) / 4, 256, 0, stream>>>(label_emb, rp_lt, cnt_lt, bkt_lt, agg_lt, NT, flag);
    title_out_kernel<<<(NT + 3) / 4, 256, 0, stream>>>(
        agg_lt, title_x, Wl_tl, bl_tl, Wr_tl, out_title, NT, flag);
}

// Round 9
// 1818.770 us; speedup vs baseline: 2.8262x; 1.7308x over previous
//
#include <hip/hip_runtime.h>
#include <hip/hip_bf16.h>

// GNN_84043920048593: hetero SAGEConv. f32 I/O (confirmed R7).
// R8: CSR gather-reduce (no f32 atomics) at 3148us; epilogues were 1.9ms of
// it (shfl-broadcast = 2 LDS-pipe ops per FMA, 50x off roofline).
// R9: register-tiled VALU GEMM epilogues (4x4 per thread, W^T in LDS).

typedef unsigned int u32;

__global__ void sentinel_kernel(float* out, int n) {
    int i = blockIdx.x * 256 + threadIdx.x;
    if (i < n) out[i] = 999.0f;
}

// ---------- CSR build: histogram -> scan -> scatter -------------------------
__global__ void __launch_bounds__(256)
hist_kernel(const int* __restrict__ dst, int* __restrict__ cnt, int n) {
    int e = blockIdx.x * 256 + threadIdx.x;
    if (e < n) atomicAdd(cnt + dst[e], 1);
}

// single-WG blocked scan: cnt[] -> rp[] (exclusive starts) and cur[] (copy)
__global__ void __launch_bounds__(1024)
scan_kernel(const int* __restrict__ cnt, int* __restrict__ rp,
            int* __restrict__ cur, int n) {
    __shared__ int part[1024];
    int t = threadIdx.x;
    int C = (n + 1023) / 1024;
    int lo = t * C, hi = min(n, lo + C);
    int sum = 0;
    for (int j = lo; j < hi; ++j) sum += cnt[j];
    part[t] = sum;
    __syncthreads();
    for (int off = 1; off < 1024; off <<= 1) {
        int v = (t >= off) ? part[t - off] : 0;
        __syncthreads();
        part[t] += v;
        __syncthreads();
    }
    int running = part[t] - sum;            // exclusive base of my chunk
    for (int j = lo; j < hi; ++j) {
        int c = cnt[j];
        rp[j] = running; cur[j] = running;
        running += c;
    }
}

__global__ void __launch_bounds__(256)
scatter_kernel(const int* __restrict__ src, const int* __restrict__ dst,
               const int* __restrict__ remap,
               int* __restrict__ cur, int* __restrict__ bucket, int n) {
    int e = blockIdx.x * 256 + threadIdx.x;
    if (e >= n) return;
    int s = src[e];
    if (remap) s = remap[s];
    int pos = atomicAdd(cur + dst[e], 1);
    bucket[pos] = s;
}

// ---------- gather-reduce: agg[i] = mean of x[bucket[rp[i]..rp[i]+cnt[i])] --
// one wave per dst node; lane = feature.
__global__ void __launch_bounds__(256)
gather_mean_kernel(const float* __restrict__ x,
                   const int* __restrict__ rp,
                   const int* __restrict__ cnt,
                   const int* __restrict__ bucket,
                   float* __restrict__ agg,
                   int n_dst)
{
    int wave = threadIdx.x >> 6, lane = threadIdx.x & 63;
    int i = blockIdx.x * 4 + wave;
    if (i >= n_dst) return;
    int st = rp[i], deg = cnt[i];
    float acc = 0.0f;
    int j = 0;
    for (; j + 1 < deg; j += 2) {
        int s0 = bucket[st + j], s1 = bucket[st + j + 1];
        acc += x[(size_t)s0 * 64 + lane] + x[(size_t)s1 * 64 + lane];
    }
    if (j < deg) acc += x[(size_t)bucket[st + j] * 64 + lane];
    agg[(size_t)i * 64 + lane] = acc / fmaxf((float)deg, 1.0f);
}

// ---------- epilogues: register-tiled GEMM, 4x4 outputs per thread ----------
// Block = 64 rows x 64 cols; thread (ty,tx) owns rows i0..i0+3, cols j0..j0+3.
// Per operand k-loop: 4 global float4 (A, L1-resident tile) + 4 ds_read_b128
// (W^T) feed 64 FMAs.

#define GEMM_OPERAND(AROW_EXPR, WLDS)                                      \
    for (int kb = 0; kb < 64; kb += 4) {                                   \
        float4 a0 = *(const float4*)((AROW_EXPR(0)) + kb);                 \
        float4 a1 = *(const float4*)((AROW_EXPR(1)) + kb);                 \
        float4 a2 = *(const float4*)((AROW_EXPR(2)) + kb);                 \
        float4 a3 = *(const float4*)((AROW_EXPR(3)) + kb);                 \
        _Pragma("unroll")                                                  \
        for (int kk = 0; kk < 4; ++kk) {                                   \
            float4 w = *(const float4*)(&WLDS[kb + kk][j0]);               \
            float av0 = ((const float*)&a0)[kk];                           \
            float av1 = ((const float*)&a1)[kk];                           \
            float av2 = ((const float*)&a2)[kk];                           \
            float av3 = ((const float*)&a3)[kk];                           \
            acc[0][0] += av0 * w.x; acc[0][1] += av0 * w.y;                \
            acc[0][2] += av0 * w.z; acc[0][3] += av0 * w.w;                \
            acc[1][0] += av1 * w.x; acc[1][1] += av1 * w.y;                \
            acc[1][2] += av1 * w.z; acc[1][3] += av1 * w.w;                \
            acc[2][0] += av2 * w.x; acc[2][1] += av2 * w.y;                \
            acc[2][2] += av2 * w.z; acc[2][3] += av2 * w.w;                \
            acc[3][0] += av3 * w.x; acc[3][1] += av3 * w.y;                \
            acc[3][2] += av3 * w.z; acc[3][3] += av3 * w.w;                \
        }                                                                  \
    }

__global__ void __launch_bounds__(256)
epi_label_kernel(const float* __restrict__ agg_tl,
                 const float* __restrict__ agg_ll,
                 const float* __restrict__ xemb,
                 const int* __restrict__ nid,
                 const float* __restrict__ Wl_tl, const float* __restrict__ bl_tl,
                 const float* __restrict__ Wr_tl,
                 const float* __restrict__ Wl_ll, const float* __restrict__ bl_ll,
                 const float* __restrict__ Wr_ll,
                 float* __restrict__ out, int n)
{
    __shared__ float wtl[64][64];   // wtl[k][j] = Wl_tl[j][k]
    __shared__ float wll[64][64];
    __shared__ float wr [64][64];   // (Wr_tl + Wr_ll)^T
    for (int idx = threadIdx.x; idx < 4096; idx += 256) {
        int k = idx >> 6, j = idx & 63;
        wtl[k][j] = Wl_tl[j * 64 + k];
        wll[k][j] = Wl_ll[j * 64 + k];
        wr [k][j] = Wr_tl[j * 64 + k] + Wr_ll[j * 64 + k];
    }
    __syncthreads();

    int ty = threadIdx.x >> 4, tx = threadIdx.x & 15;
    int i0 = blockIdx.x * 64 + ty * 4;
    int j0 = tx * 4;

    // clamped row indices for loads; stores guarded
    int r0 = min(i0 + 0, n - 1), r1 = min(i0 + 1, n - 1);
    int r2 = min(i0 + 2, n - 1), r3 = min(i0 + 3, n - 1);
    int rr[4] = {r0, r1, r2, r3};
    int nd[4] = {nid[r0], nid[r1], nid[r2], nid[r3]};

    float4 bias;
    bias.x = bl_tl[j0+0] + bl_ll[j0+0];
    bias.y = bl_tl[j0+1] + bl_ll[j0+1];
    bias.z = bl_tl[j0+2] + bl_ll[j0+2];
    bias.w = bl_tl[j0+3] + bl_ll[j0+3];
    float acc[4][4];
    #pragma unroll
    for (int r = 0; r < 4; ++r) {
        acc[r][0] = bias.x; acc[r][1] = bias.y;
        acc[r][2] = bias.z; acc[r][3] = bias.w;
    }

    #define ATL_ROW(r) (agg_tl + (size_t)rr[r] * 64)
    #define ALL_ROW(r) (agg_ll + (size_t)rr[r] * 64)
    #define XEM_ROW(r) (xemb  + (size_t)nd[r] * 64)
    GEMM_OPERAND(ATL_ROW, wtl)
    GEMM_OPERAND(ALL_ROW, wll)
    GEMM_OPERAND(XEM_ROW, wr)
    #undef ATL_ROW
    #undef ALL_ROW
    #undef XEM_ROW

    #pragma unroll
    for (int r = 0; r < 4; ++r) {
        if (i0 + r < n) {
            float4 o;
            o.x = fmaxf(acc[r][0], 0.0f); o.y = fmaxf(acc[r][1], 0.0f);
            o.z = fmaxf(acc[r][2], 0.0f); o.w = fmaxf(acc[r][3], 0.0f);
            *(float4*)(out + (size_t)(i0 + r) * 64 + j0) = o;
        }
    }
}

__global__ void __launch_bounds__(256)
epi_title_kernel(const float* __restrict__ agg_lt,
                 const float* __restrict__ title_x,
                 const float* __restrict__ Wl_tl, const float* __restrict__ bl_tl,
                 const float* __restrict__ Wr_tl,
                 float* __restrict__ out, int n)
{
    __shared__ float wl[64][64];
    __shared__ float wr[64][64];
    for (int idx = threadIdx.x; idx < 4096; idx += 256) {
        int k = idx >> 6, j = idx & 63;
        wl[k][j] = Wl_tl[j * 64 + k];
        wr[k][j] = Wr_tl[j * 64 + k];
    }
    __syncthreads();

    int ty = threadIdx.x >> 4, tx = threadIdx.x & 15;
    int i0 = blockIdx.x * 64 + ty * 4;
    int j0 = tx * 4;

    int rr[4] = {min(i0 + 0, n - 1), min(i0 + 1, n - 1),
                 min(i0 + 2, n - 1), min(i0 + 3, n - 1)};

    float4 bias = *(const float4*)(bl_tl + j0);
    float acc[4][4];
    #pragma unroll
    for (int r = 0; r < 4; ++r) {
        acc[r][0] = bias.x; acc[r][1] = bias.y;
        acc[r][2] = bias.z; acc[r][3] = bias.w;
    }

    #define ALT_ROW(r) (agg_lt  + (size_t)rr[r] * 64)
    #define TXX_ROW(r) (title_x + (size_t)rr[r] * 64)
    GEMM_OPERAND(ALT_ROW, wl)
    GEMM_OPERAND(TXX_ROW, wr)
    #undef ALT_ROW
    #undef TXX_ROW

    #pragma unroll
    for (int r = 0; r < 4; ++r) {
        if (i0 + r < n) {
            float4 o;
            o.x = fmaxf(acc[r][0], 0.0f); o.y = fmaxf(acc[r][1], 0.0f);
            o.z = fmaxf(acc[r][2], 0.0f); o.w = fmaxf(acc[r][3], 0.0f);
            *(float4*)(out + (size_t)(i0 + r) * 64 + j0) = o;
        }
    }
}

extern "C" void kernel_launch(void* const* d_in, const int* in_sizes, int n_in,
                              void* d_out, int out_size, void* d_ws, size_t ws_size,
                              hipStream_t stream)
{
    const float* title_x   = (const float*)d_in[0];
    const float* label_emb = (const float*)d_in[1];
    const float* Wl_tl     = (const float*)d_in[2];
    const float* bl_tl     = (const float*)d_in[3];
    const float* Wr_tl     = (const float*)d_in[4];
    const float* Wl_ll     = (const float*)d_in[5];
    const float* bl_ll     = (const float*)d_in[6];
    const float* Wr_ll     = (const float*)d_in[7];
    const int* label_node_id = (const int*)d_in[8];
    const int* tl_src = (const int*)d_in[9];
    const int* tl_dst = (const int*)d_in[10];
    const int* lt_src = (const int*)d_in[11];
    const int* lt_dst = (const int*)d_in[12];
    const int* ll_src = (const int*)d_in[13];
    const int* ll_dst = (const int*)d_in[14];

    const int NT  = in_sizes[0] / 64;
    const int NL  = in_sizes[8];
    const int eTL = in_sizes[9];
    const int eLT = in_sizes[11];
    const int eLL = in_sizes[13];

    // ---- workspace overlay --------------------------------------------------
    size_t szAgL = (size_t)NL * 64 * 4;       // one label agg: 25.6 MB
    size_t szAgT = (size_t)NT * 64 * 4;       // title agg:     51.2 MB
    size_t iNL   = (size_t)NL * 4;
    size_t iNT   = (size_t)NT * 4;

    size_t regionA = 2 * szAgL + 6 * iNL + ((size_t)eTL + eLL) * 4;  // ~63 MB
    size_t regionB = szAgT + 3 * iNT + (size_t)eLT * 4;              // ~60 MB
    size_t big     = regionA > regionB ? regionA : regionB;
    size_t needed  = big;

    float* out_label = (float*)d_out;
    float* out_title = out_label + (size_t)NL * 64;

    if (ws_size < needed) {  // diagnosable failure: absmax ~999
        sentinel_kernel<<<(out_size + 255) / 256, 256, 0, stream>>>((float*)d_out, out_size);
        return;
    }

    char* base = (char*)d_ws;
    // phase A layout
    float* agg_tl = (float*)(base);
    float* agg_ll = (float*)(base + szAgL);
    int* cnt_tl = (int*)(base + 2 * szAgL);
    int* cnt_ll = (int*)(base + 2 * szAgL + iNL);
    int* rp_tl  = (int*)(base + 2 * szAgL + 2 * iNL);
    int* rp_ll  = (int*)(base + 2 * szAgL + 3 * iNL);
    int* cur_tl = (int*)(base + 2 * szAgL + 4 * iNL);
    int* cur_ll = (int*)(base + 2 * szAgL + 5 * iNL);
    int* bkt_tl = (int*)(base + 2 * szAgL + 6 * iNL);
    int* bkt_ll = bkt_tl + eTL;
    // phase B layout (overlays A; stream-ordered)
    float* agg_lt = (float*)(base);
    int* cnt_lt = (int*)(base + szAgT);
    int* rp_lt  = (int*)(base + szAgT + iNT);
    int* cur_lt = (int*)(base + szAgT + 2 * iNT);
    int* bkt_lt = (int*)(base + szAgT + 3 * iNT);

    auto eblk = [](int n) { return (n + 255) / 256; };

    // ---- phase A: label destination ----------------------------------------
    (void)hipMemsetAsync(cnt_tl, 0, 2 * iNL, stream);   // cnt_tl + cnt_ll
    hist_kernel<<<eblk(eTL), 256, 0, stream>>>(tl_dst, cnt_tl, eTL);
    hist_kernel<<<eblk(eLL), 256, 0, stream>>>(ll_dst, cnt_ll, eLL);
    scan_kernel<<<1, 1024, 0, stream>>>(cnt_tl, rp_tl, cur_tl, NL);
    scan_kernel<<<1, 1024, 0, stream>>>(cnt_ll, rp_ll, cur_ll, NL);
    scatter_kernel<<<eblk(eTL), 256, 0, stream>>>(tl_src, tl_dst, nullptr, cur_tl, bkt_tl, eTL);
    scatter_kernel<<<eblk(eLL), 256, 0, stream>>>(ll_src, ll_dst, label_node_id, cur_ll, bkt_ll, eLL);
    gather_mean_kernel<<<(NL + 3) / 4, 256, 0, stream>>>(title_x,   rp_tl, cnt_tl, bkt_tl, agg_tl, NL);
    gather_mean_kernel<<<(NL + 3) / 4, 256, 0, stream>>>(label_emb, rp_ll, cnt_ll, bkt_ll, agg_ll, NL);
    epi_label_kernel<<<(NL + 63) / 64, 256, 0, stream>>>(
        agg_tl, agg_ll, label_emb, label_node_id,
        Wl_tl, bl_tl, Wr_tl, Wl_ll, bl_ll, Wr_ll, out_label, NL);

    // ---- phase B: title destination (stream-ordered reuse) -----------------
    (void)hipMemsetAsync(cnt_lt, 0, iNT, stream);
    hist_kernel<<<eblk(eLT), 256, 0, stream>>>(lt_dst, cnt_lt, eLT);
    scan_kernel<<<1, 1024, 0, stream>>>(cnt_lt, rp_lt, cur_lt, NT);
    scatter_kernel<<<eblk(eLT), 256, 0, stream>>>(lt_src, lt_dst, label_node_id, cur_lt, bkt_lt, eLT);
    gather_mean_kernel<<<(NT + 3) / 4, 256, 0, stream>>>(label_emb, rp_lt, cnt_lt, bkt_lt, agg_lt, NT);
    epi_title_kernel<<<(NT + 63) / 64, 256, 0, stream>>>(
        agg_lt, title_x, Wl_tl, bl_tl, Wr_tl, out_title, NT);
}

// Round 10
// 942.106 us; speedup vs baseline: 5.4562x; 1.9305x over previous
//
#include <hip/hip_runtime.h>
#include <hip/hip_bf16.h>

// GNN_84043920048593: hetero SAGEConv. f32 I/O (confirmed R7).
// R8: CSR pivot, 3148us. R9: reg-tiled epilogues, 1819us — but single-WG
// scan_kernel was 460us x3 (1 CU, uncoalesced serial walk).
// R10: hierarchical scan (reduce -> scan bsums -> apply), all coalesced.

typedef unsigned int u32;

__global__ void sentinel_kernel(float* out, int n) {
    int i = blockIdx.x * 256 + threadIdx.x;
    if (i < n) out[i] = 999.0f;
}

// ---------- CSR build: histogram -> hierarchical scan -> scatter ------------
__global__ void __launch_bounds__(256)
hist_kernel(const int* __restrict__ dst, int* __restrict__ cnt, int n) {
    int e = blockIdx.x * 256 + threadIdx.x;
    if (e < n) atomicAdd(cnt + dst[e], 1);
}

// phase 1: block b sums cnt[b*2048 .. b*2048+2048)
__global__ void __launch_bounds__(256)
scan_reduce_kernel(const int* __restrict__ cnt, int* __restrict__ bsum, int n) {
    __shared__ int sh[256];
    int base = blockIdx.x * 2048;
    int s = 0;
    #pragma unroll
    for (int k = 0; k < 8; ++k) {
        int idx = base + k * 256 + threadIdx.x;
        if (idx < n) s += cnt[idx];
    }
    sh[threadIdx.x] = s;
    __syncthreads();
    for (int off = 128; off > 0; off >>= 1) {
        if (threadIdx.x < off) sh[threadIdx.x] += sh[threadIdx.x + off];
        __syncthreads();
    }
    if (threadIdx.x == 0) bsum[blockIdx.x] = sh[0];
}

// phase 2: exclusive scan of block sums in place (nb <= 1024)
__global__ void __launch_bounds__(1024)
scan_bsum_kernel(int* __restrict__ bsum, int nb) {
    __shared__ int sh[1024];
    int t = threadIdx.x;
    int v = (t < nb) ? bsum[t] : 0;
    sh[t] = v;
    __syncthreads();
    for (int off = 1; off < 1024; off <<= 1) {
        int u = (t >= off) ? sh[t - off] : 0;
        __syncthreads();
        sh[t] += u;
        __syncthreads();
    }
    if (t < nb) bsum[t] = sh[t] - v;   // exclusive
}

// phase 3: local scan + global offset -> rp (exclusive starts) and cur (copy)
__global__ void __launch_bounds__(256)
scan_apply_kernel(const int* __restrict__ cnt, const int* __restrict__ bsum,
                  int* __restrict__ rp, int* __restrict__ cur, int n) {
    __shared__ int sh[256];
    int lo = blockIdx.x * 2048 + threadIdx.x * 8;
    int v[8];
    int s = 0;
    #pragma unroll
    for (int k = 0; k < 8; ++k) {
        int idx = lo + k;
        v[k] = (idx < n) ? cnt[idx] : 0;
        s += v[k];
    }
    sh[threadIdx.x] = s;
    __syncthreads();
    for (int off = 1; off < 256; off <<= 1) {
        int u = (threadIdx.x >= off) ? sh[threadIdx.x - off] : 0;
        __syncthreads();
        sh[threadIdx.x] += u;
        __syncthreads();
    }
    int run = bsum[blockIdx.x] + sh[threadIdx.x] - s;  // exclusive base
    #pragma unroll
    for (int k = 0; k < 8; ++k) {
        int idx = lo + k;
        if (idx < n) { rp[idx] = run; cur[idx] = run; run += v[k]; }
    }
}

__global__ void __launch_bounds__(256)
scatter_kernel(const int* __restrict__ src, const int* __restrict__ dst,
               const int* __restrict__ remap,
               int* __restrict__ cur, int* __restrict__ bucket, int n) {
    int e = blockIdx.x * 256 + threadIdx.x;
    if (e >= n) return;
    int s = src[e];
    if (remap) s = remap[s];
    int pos = atomicAdd(cur + dst[e], 1);
    bucket[pos] = s;
}

// ---------- gather-reduce: agg[i] = mean of x[bucket[rp[i]..rp[i]+cnt[i])] --
__global__ void __launch_bounds__(256)
gather_mean_kernel(const float* __restrict__ x,
                   const int* __restrict__ rp,
                   const int* __restrict__ cnt,
                   const int* __restrict__ bucket,
                   float* __restrict__ agg,
                   int n_dst)
{
    int wave = threadIdx.x >> 6, lane = threadIdx.x & 63;
    int i = blockIdx.x * 4 + wave;
    if (i >= n_dst) return;
    int st = rp[i], deg = cnt[i];
    float acc = 0.0f;
    int j = 0;
    for (; j + 1 < deg; j += 2) {
        int s0 = bucket[st + j], s1 = bucket[st + j + 1];
        acc += x[(size_t)s0 * 64 + lane] + x[(size_t)s1 * 64 + lane];
    }
    if (j < deg) acc += x[(size_t)bucket[st + j] * 64 + lane];
    agg[(size_t)i * 64 + lane] = acc / fmaxf((float)deg, 1.0f);
}

// ---------- epilogues: register-tiled GEMM, 4x4 outputs per thread ----------
#define GEMM_OPERAND(AROW_EXPR, WLDS)                                      \
    for (int kb = 0; kb < 64; kb += 4) {                                   \
        float4 a0 = *(const float4*)((AROW_EXPR(0)) + kb);                 \
        float4 a1 = *(const float4*)((AROW_EXPR(1)) + kb);                 \
        float4 a2 = *(const float4*)((AROW_EXPR(2)) + kb);                 \
        float4 a3 = *(const float4*)((AROW_EXPR(3)) + kb);                 \
        _Pragma("unroll")                                                  \
        for (int kk = 0; kk < 4; ++kk) {                                   \
            float4 w = *(const float4*)(&WLDS[kb + kk][j0]);               \
            float av0 = ((const float*)&a0)[kk];                           \
            float av1 = ((const float*)&a1)[kk];                           \
            float av2 = ((const float*)&a2)[kk];                           \
            float av3 = ((const float*)&a3)[kk];                           \
            acc[0][0] += av0 * w.x; acc[0][1] += av0 * w.y;                \
            acc[0][2] += av0 * w.z; acc[0][3] += av0 * w.w;                \
            acc[1][0] += av1 * w.x; acc[1][1] += av1 * w.y;                \
            acc[1][2] += av1 * w.z; acc[1][3] += av1 * w.w;                \
            acc[2][0] += av2 * w.x; acc[2][1] += av2 * w.y;                \
            acc[2][2] += av2 * w.z; acc[2][3] += av2 * w.w;                \
            acc[3][0] += av3 * w.x; acc[3][1] += av3 * w.y;                \
            acc[3][2] += av3 * w.z; acc[3][3] += av3 * w.w;                \
        }                                                                  \
    }

__global__ void __launch_bounds__(256)
epi_label_kernel(const float* __restrict__ agg_tl,
                 const float* __restrict__ agg_ll,
                 const float* __restrict__ xemb,
                 const int* __restrict__ nid,
                 const float* __restrict__ Wl_tl, const float* __restrict__ bl_tl,
                 const float* __restrict__ Wr_tl,
                 const float* __restrict__ Wl_ll, const float* __restrict__ bl_ll,
                 const float* __restrict__ Wr_ll,
                 float* __restrict__ out, int n)
{
    __shared__ float wtl[64][64];   // wtl[k][j] = Wl_tl[j][k]
    __shared__ float wll[64][64];
    __shared__ float wr [64][64];   // (Wr_tl + Wr_ll)^T
    for (int idx = threadIdx.x; idx < 4096; idx += 256) {
        int k = idx >> 6, j = idx & 63;
        wtl[k][j] = Wl_tl[j * 64 + k];
        wll[k][j] = Wl_ll[j * 64 + k];
        wr [k][j] = Wr_tl[j * 64 + k] + Wr_ll[j * 64 + k];
    }
    __syncthreads();

    int ty = threadIdx.x >> 4, tx = threadIdx.x & 15;
    int i0 = blockIdx.x * 64 + ty * 4;
    int j0 = tx * 4;

    int rr[4] = {min(i0 + 0, n - 1), min(i0 + 1, n - 1),
                 min(i0 + 2, n - 1), min(i0 + 3, n - 1)};
    int nd[4] = {nid[rr[0]], nid[rr[1]], nid[rr[2]], nid[rr[3]]};

    float4 bias;
    bias.x = bl_tl[j0+0] + bl_ll[j0+0];
    bias.y = bl_tl[j0+1] + bl_ll[j0+1];
    bias.z = bl_tl[j0+2] + bl_ll[j0+2];
    bias.w = bl_tl[j0+3] + bl_ll[j0+3];
    float acc[4][4];
    #pragma unroll
    for (int r = 0; r < 4; ++r) {
        acc[r][0] = bias.x; acc[r][1] = bias.y;
        acc[r][2] = bias.z; acc[r][3] = bias.w;
    }

    #define ATL_ROW(r) (agg_tl + (size_t)rr[r] * 64)
    #define ALL_ROW(r) (agg_ll + (size_t)rr[r] * 64)
    #define XEM_ROW(r) (xemb  + (size_t)nd[r] * 64)
    GEMM_OPERAND(ATL_ROW, wtl)
    GEMM_OPERAND(ALL_ROW, wll)
    GEMM_OPERAND(XEM_ROW, wr)
    #undef ATL_ROW
    #undef ALL_ROW
    #undef XEM_ROW

    #pragma unroll
    for (int r = 0; r < 4; ++r) {
        if (i0 + r < n) {
            float4 o;
            o.x = fmaxf(acc[r][0], 0.0f); o.y = fmaxf(acc[r][1], 0.0f);
            o.z = fmaxf(acc[r][2], 0.0f); o.w = fmaxf(acc[r][3], 0.0f);
            *(float4*)(out + (size_t)(i0 + r) * 64 + j0) = o;
        }
    }
}

__global__ void __launch_bounds__(256)
epi_title_kernel(const float* __restrict__ agg_lt,
                 const float* __restrict__ title_x,
                 const float* __restrict__ Wl_tl, const float* __restrict__ bl_tl,
                 const float* __restrict__ Wr_tl,
                 float* __restrict__ out, int n)
{
    __shared__ float wl[64][64];
    __shared__ float wr[64][64];
    for (int idx = threadIdx.x; idx < 4096; idx += 256) {
        int k = idx >> 6, j = idx & 63;
        wl[k][j] = Wl_tl[j * 64 + k];
        wr[k][j] = Wr_tl[j * 64 + k];
    }
    __syncthreads();

    int ty = threadIdx.x >> 4, tx = threadIdx.x & 15;
    int i0 = blockIdx.x * 64 + ty * 4;
    int j0 = tx * 4;

    int rr[4] = {min(i0 + 0, n - 1), min(i0 + 1, n - 1),
                 min(i0 + 2, n - 1), min(i0 + 3, n - 1)};

    float4 bias = *(const float4*)(bl_tl + j0);
    float acc[4][4];
    #pragma unroll
    for (int r = 0; r < 4; ++r) {
        acc[r][0] = bias.x; acc[r][1] = bias.y;
        acc[r][2] = bias.z; acc[r][3] = bias.w;
    }

    #define ALT_ROW(r) (agg_lt  + (size_t)rr[r] * 64)
    #define TXX_ROW(r) (title_x + (size_t)rr[r] * 64)
    GEMM_OPERAND(ALT_ROW, wl)
    GEMM_OPERAND(TXX_ROW, wr)
    #undef ALT_ROW
    #undef TXX_ROW

    #pragma unroll
    for (int r = 0; r < 4; ++r) {
        if (i0 + r < n) {
            float4 o;
            o.x = fmaxf(acc[r][0], 0.0f); o.y = fmaxf(acc[r][1], 0.0f);
            o.z = fmaxf(acc[r][2], 0.0f); o.w = fmaxf(acc[r][3], 0.0f);
            *(float4*)(out + (size_t)(i0 + r) * 64 + j0) = o;
        }
    }
}

extern "C" void kernel_launch(void* const* d_in, const int* in_sizes, int n_in,
                              void* d_out, int out_size, void* d_ws, size_t ws_size,
                              hipStream_t stream)
{
    const float* title_x   = (const float*)d_in[0];
    const float* label_emb = (const float*)d_in[1];
    const float* Wl_tl     = (const float*)d_in[2];
    const float* bl_tl     = (const float*)d_in[3];
    const float* Wr_tl     = (const float*)d_in[4];
    const float* Wl_ll     = (const float*)d_in[5];
    const float* bl_ll     = (const float*)d_in[6];
    const float* Wr_ll     = (const float*)d_in[7];
    const int* label_node_id = (const int*)d_in[8];
    const int* tl_src = (const int*)d_in[9];
    const int* tl_dst = (const int*)d_in[10];
    const int* lt_src = (const int*)d_in[11];
    const int* lt_dst = (const int*)d_in[12];
    const int* ll_src = (const int*)d_in[13];
    const int* ll_dst = (const int*)d_in[14];

    const int NT  = in_sizes[0] / 64;
    const int NL  = in_sizes[8];
    const int eTL = in_sizes[9];
    const int eLT = in_sizes[11];
    const int eLL = in_sizes[13];

    // ---- workspace overlay --------------------------------------------------
    size_t szAgL = (size_t)NL * 64 * 4;       // one label agg: 25.6 MB
    size_t szAgT = (size_t)NT * 64 * 4;       // title agg:     51.2 MB
    size_t iNL   = (size_t)NL * 4;
    size_t iNT   = (size_t)NT * 4;
    size_t szBs  = 1024 * 4;                  // block sums (<=1024 blocks)

    size_t regionA = 2 * szAgL + 6 * iNL + ((size_t)eTL + eLL) * 4;  // ~63 MB
    size_t regionB = szAgT + 3 * iNT + (size_t)eLT * 4;              // ~60 MB
    size_t big     = regionA > regionB ? regionA : regionB;
    size_t needed  = big + szBs;

    float* out_label = (float*)d_out;
    float* out_title = out_label + (size_t)NL * 64;

    if (ws_size < needed) {  // diagnosable failure: absmax ~999
        sentinel_kernel<<<(out_size + 255) / 256, 256, 0, stream>>>((float*)d_out, out_size);
        return;
    }

    char* base = (char*)d_ws;
    // phase A layout
    float* agg_tl = (float*)(base);
    float* agg_ll = (float*)(base + szAgL);
    int* cnt_tl = (int*)(base + 2 * szAgL);
    int* cnt_ll = (int*)(base + 2 * szAgL + iNL);
    int* rp_tl  = (int*)(base + 2 * szAgL + 2 * iNL);
    int* rp_ll  = (int*)(base + 2 * szAgL + 3 * iNL);
    int* cur_tl = (int*)(base + 2 * szAgL + 4 * iNL);
    int* cur_ll = (int*)(base + 2 * szAgL + 5 * iNL);
    int* bkt_tl = (int*)(base + 2 * szAgL + 6 * iNL);
    int* bkt_ll = bkt_tl + eTL;
    // phase B layout (overlays A; stream-ordered)
    float* agg_lt = (float*)(base);
    int* cnt_lt = (int*)(base + szAgT);
    int* rp_lt  = (int*)(base + szAgT + iNT);
    int* cur_lt = (int*)(base + szAgT + 2 * iNT);
    int* bkt_lt = (int*)(base + szAgT + 3 * iNT);
    int* bsum   = (int*)(base + big);          // shared by all scans (serial)

    auto eblk = [](int n) { return (n + 255) / 256; };
    auto sblk = [](int n) { return (n + 2047) / 2048; };

    auto scan = [&](const int* cnt, int* rp, int* cur, int n) {
        int nb = sblk(n);
        scan_reduce_kernel<<<nb, 256, 0, stream>>>(cnt, bsum, n);
        scan_bsum_kernel<<<1, 1024, 0, stream>>>(bsum, nb);
        scan_apply_kernel<<<nb, 256, 0, stream>>>(cnt, bsum, rp, cur, n);
    };

    // ---- phase A: label destination ----------------------------------------
    (void)hipMemsetAsync(cnt_tl, 0, 2 * iNL, stream);   // cnt_tl + cnt_ll
    hist_kernel<<<eblk(eTL), 256, 0, stream>>>(tl_dst, cnt_tl, eTL);
    hist_kernel<<<eblk(eLL), 256, 0, stream>>>(ll_dst, cnt_ll, eLL);
    scan(cnt_tl, rp_tl, cur_tl, NL);
    scan(cnt_ll, rp_ll, cur_ll, NL);
    scatter_kernel<<<eblk(eTL), 256, 0, stream>>>(tl_src, tl_dst, nullptr, cur_tl, bkt_tl, eTL);
    scatter_kernel<<<eblk(eLL), 256, 0, stream>>>(ll_src, ll_dst, label_node_id, cur_ll, bkt_ll, eLL);
    gather_mean_kernel<<<(NL + 3) / 4, 256, 0, stream>>>(title_x,   rp_tl, cnt_tl, bkt_tl, agg_tl, NL);
    gather_mean_kernel<<<(NL + 3) / 4, 256, 0, stream>>>(label_emb, rp_ll, cnt_ll, bkt_ll, agg_ll, NL);
    epi_label_kernel<<<(NL + 63) / 64, 256, 0, stream>>>(
        agg_tl, agg_ll, label_emb, label_node_id,
        Wl_tl, bl_tl, Wr_tl, Wl_ll, bl_ll, Wr_ll, out_label, NL);

    // ---- phase B: title destination (stream-ordered reuse) -----------------
    (void)hipMemsetAsync(cnt_lt, 0, iNT, stream);
    hist_kernel<<<eblk(eLT), 256, 0, stream>>>(lt_dst, cnt_lt, eLT);
    scan(cnt_lt, rp_lt, cur_lt, NT);
    scatter_kernel<<<eblk(eLT), 256, 0, stream>>>(lt_src, lt_dst, label_node_id, cur_lt, bkt_lt, eLT);
    gather_mean_kernel<<<(NT + 3) / 4, 256, 0, stream>>>(label_emb, rp_lt, cnt_lt, bkt_lt, agg_lt, NT);
    epi_title_kernel<<<(NT + 63) / 64, 256, 0, stream>>>(
        agg_lt, title_x, Wl_tl, bl_tl, Wr_tl, out_title, NT);
}

// Round 11
// 941.933 us; speedup vs baseline: 5.4572x; 1.0002x over previous
//
#include <hip/hip_runtime.h>
#include <hip/hip_bf16.h>

// GNN_84043920048593: hetero SAGEConv. f32 I/O (confirmed R7).
// R8 CSR pivot 3148us; R9 reg-tiled epilogues 1819us; R10 hierarchical scan
// 942us. R11: scatter stores -> atomicExch (memory-side 4B, no 64B line
// write-allocate; evidence R7: atomics = 6.4B/op vs 16x for plain stores) +
// gather reads 4 rows/iter (1KB per wave instruction, 4x MLP).

typedef unsigned int u32;

__global__ void sentinel_kernel(float* out, int n) {
    int i = blockIdx.x * 256 + threadIdx.x;
    if (i < n) out[i] = 999.0f;
}

// ---------- CSR build: histogram -> hierarchical scan -> scatter ------------
__global__ void __launch_bounds__(256)
hist_kernel(const int* __restrict__ dst, int* __restrict__ cnt, int n) {
    int e = blockIdx.x * 256 + threadIdx.x;
    if (e < n) atomicAdd(cnt + dst[e], 1);
}

// phase 1: block b sums cnt[b*2048 .. b*2048+2048)
__global__ void __launch_bounds__(256)
scan_reduce_kernel(const int* __restrict__ cnt, int* __restrict__ bsum, int n) {
    __shared__ int sh[256];
    int base = blockIdx.x * 2048;
    int s = 0;
    #pragma unroll
    for (int k = 0; k < 8; ++k) {
        int idx = base + k * 256 + threadIdx.x;
        if (idx < n) s += cnt[idx];
    }
    sh[threadIdx.x] = s;
    __syncthreads();
    for (int off = 128; off > 0; off >>= 1) {
        if (threadIdx.x < off) sh[threadIdx.x] += sh[threadIdx.x + off];
        __syncthreads();
    }
    if (threadIdx.x == 0) bsum[blockIdx.x] = sh[0];
}

// phase 2: exclusive scan of block sums in place (nb <= 1024)
__global__ void __launch_bounds__(1024)
scan_bsum_kernel(int* __restrict__ bsum, int nb) {
    __shared__ int sh[1024];
    int t = threadIdx.x;
    int v = (t < nb) ? bsum[t] : 0;
    sh[t] = v;
    __syncthreads();
    for (int off = 1; off < 1024; off <<= 1) {
        int u = (t >= off) ? sh[t - off] : 0;
        __syncthreads();
        sh[t] += u;
        __syncthreads();
    }
    if (t < nb) bsum[t] = sh[t] - v;   // exclusive
}

// phase 3: local scan + global offset -> rp (exclusive starts) and cur (copy)
__global__ void __launch_bounds__(256)
scan_apply_kernel(const int* __restrict__ cnt, const int* __restrict__ bsum,
                  int* __restrict__ rp, int* __restrict__ cur, int n) {
    __shared__ int sh[256];
    int lo = blockIdx.x * 2048 + threadIdx.x * 8;
    int v[8];
    int s = 0;
    #pragma unroll
    for (int k = 0; k < 8; ++k) {
        int idx = lo + k;
        v[k] = (idx < n) ? cnt[idx] : 0;
        s += v[k];
    }
    sh[threadIdx.x] = s;
    __syncthreads();
    for (int off = 1; off < 256; off <<= 1) {
        int u = (threadIdx.x >= off) ? sh[threadIdx.x - off] : 0;
        __syncthreads();
        sh[threadIdx.x] += u;
        __syncthreads();
    }
    int run = bsum[blockIdx.x] + sh[threadIdx.x] - s;  // exclusive base
    #pragma unroll
    for (int k = 0; k < 8; ++k) {
        int idx = lo + k;
        if (idx < n) { rp[idx] = run; cur[idx] = run; run += v[k]; }
    }
}

// scatter: bucket write via atomicExch — memory-side 4B op, avoids the 64B
// line write-allocate amplification measured in R10 (105MB for 6.4MB payload)
__global__ void __launch_bounds__(256)
scatter_kernel(const int* __restrict__ src, const int* __restrict__ dst,
               const int* __restrict__ remap,
               int* __restrict__ cur, int* __restrict__ bucket, int n) {
    int e = blockIdx.x * 256 + threadIdx.x;
    if (e >= n) return;
    int s = src[e];
    if (remap) s = remap[s];
    int pos = atomicAdd(cur + dst[e], 1);
    (void)atomicExch(bucket + pos, s);
}

// ---------- gather-reduce: 4 rows per wave-iteration ------------------------
// lane = (q = row slot 0..3, c = 16B chunk 0..15); wave reads 1KB/instruction.
__global__ void __launch_bounds__(256)
gather_mean_kernel(const float* __restrict__ x,
                   const int* __restrict__ rp,
                   const int* __restrict__ cnt,
                   const int* __restrict__ bucket,
                   float* __restrict__ agg,
                   int n_dst)
{
    int wave = threadIdx.x >> 6, lane = threadIdx.x & 63;
    int i = blockIdx.x * 4 + wave;
    if (i >= n_dst) return;
    int st = rp[i], deg = cnt[i];
    int q = lane >> 4, c = lane & 15;
    float4 acc = make_float4(0.f, 0.f, 0.f, 0.f);
    for (int j = 0; j < deg; j += 4) {
        int idx = j + q;
        int r = bucket[st + min(idx, deg - 1)];   // broadcast across 16 lanes
        float m = (idx < deg) ? 1.0f : 0.0f;
        float4 v = ((const float4*)x)[(size_t)r * 16 + c];
        acc.x += m * v.x; acc.y += m * v.y;
        acc.z += m * v.z; acc.w += m * v.w;
    }
    // reduce across the 4 row slots (lanes differing in bits 4,5)
    acc.x += __shfl_xor(acc.x, 16); acc.y += __shfl_xor(acc.y, 16);
    acc.z += __shfl_xor(acc.z, 16); acc.w += __shfl_xor(acc.w, 16);
    acc.x += __shfl_xor(acc.x, 32); acc.y += __shfl_xor(acc.y, 32);
    acc.z += __shfl_xor(acc.z, 32); acc.w += __shfl_xor(acc.w, 32);
    if (q == 0) {
        float inv = 1.0f / fmaxf((float)deg, 1.0f);
        float4 o = make_float4(acc.x * inv, acc.y * inv, acc.z * inv, acc.w * inv);
        ((float4*)agg)[(size_t)i * 16 + c] = o;
    }
}

// ---------- epilogues: register-tiled GEMM, 4x4 outputs per thread ----------
#define GEMM_OPERAND(AROW_EXPR, WLDS)                                      \
    for (int kb = 0; kb < 64; kb += 4) {                                   \
        float4 a0 = *(const float4*)((AROW_EXPR(0)) + kb);                 \
        float4 a1 = *(const float4*)((AROW_EXPR(1)) + kb);                 \
        float4 a2 = *(const float4*)((AROW_EXPR(2)) + kb);                 \
        float4 a3 = *(const float4*)((AROW_EXPR(3)) + kb);                 \
        _Pragma("unroll")                                                  \
        for (int kk = 0; kk < 4; ++kk) {                                   \
            float4 w = *(const float4*)(&WLDS[kb + kk][j0]);               \
            float av0 = ((const float*)&a0)[kk];                           \
            float av1 = ((const float*)&a1)[kk];                           \
            float av2 = ((const float*)&a2)[kk];                           \
            float av3 = ((const float*)&a3)[kk];                           \
            acc[0][0] += av0 * w.x; acc[0][1] += av0 * w.y;                \
            acc[0][2] += av0 * w.z; acc[0][3] += av0 * w.w;                \
            acc[1][0] += av1 * w.x; acc[1][1] += av1 * w.y;                \
            acc[1][2] += av1 * w.z; acc[1][3] += av1 * w.w;                \
            acc[2][0] += av2 * w.x; acc[2][1] += av2 * w.y;                \
            acc[2][2] += av2 * w.z; acc[2][3] += av2 * w.w;                \
            acc[3][0] += av3 * w.x; acc[3][1] += av3 * w.y;                \
            acc[3][2] += av3 * w.z; acc[3][3] += av3 * w.w;                \
        }                                                                  \
    }

__global__ void __launch_bounds__(256)
epi_label_kernel(const float* __restrict__ agg_tl,
                 const float* __restrict__ agg_ll,
                 const float* __restrict__ xemb,
                 const int* __restrict__ nid,
                 const float* __restrict__ Wl_tl, const float* __restrict__ bl_tl,
                 const float* __restrict__ Wr_tl,
                 const float* __restrict__ Wl_ll, const float* __restrict__ bl_ll,
                 const float* __restrict__ Wr_ll,
                 float* __restrict__ out, int n)
{
    __shared__ float wtl[64][64];   // wtl[k][j] = Wl_tl[j][k]
    __shared__ float wll[64][64];
    __shared__ float wr [64][64];   // (Wr_tl + Wr_ll)^T
    for (int idx = threadIdx.x; idx < 4096; idx += 256) {
        int k = idx >> 6, j = idx & 63;
        wtl[k][j] = Wl_tl[j * 64 + k];
        wll[k][j] = Wl_ll[j * 64 + k];
        wr [k][j] = Wr_tl[j * 64 + k] + Wr_ll[j * 64 + k];
    }
    __syncthreads();

    int ty = threadIdx.x >> 4, tx = threadIdx.x & 15;
    int i0 = blockIdx.x * 64 + ty * 4;
    int j0 = tx * 4;

    int rr[4] = {min(i0 + 0, n - 1), min(i0 + 1, n - 1),
                 min(i0 + 2, n - 1), min(i0 + 3, n - 1)};
    int nd[4] = {nid[rr[0]], nid[rr[1]], nid[rr[2]], nid[rr[3]]};

    float4 bias;
    bias.x = bl_tl[j0+0] + bl_ll[j0+0];
    bias.y = bl_tl[j0+1] + bl_ll[j0+1];
    bias.z = bl_tl[j0+2] + bl_ll[j0+2];
    bias.w = bl_tl[j0+3] + bl_ll[j0+3];
    float acc[4][4];
    #pragma unroll
    for (int r = 0; r < 4; ++r) {
        acc[r][0] = bias.x; acc[r][1] = bias.y;
        acc[r][2] = bias.z; acc[r][3] = bias.w;
    }

    #define ATL_ROW(r) (agg_tl + (size_t)rr[r] * 64)
    #define ALL_ROW(r) (agg_ll + (size_t)rr[r] * 64)
    #define XEM_ROW(r) (xemb  + (size_t)nd[r] * 64)
    GEMM_OPERAND(ATL_ROW, wtl)
    GEMM_OPERAND(ALL_ROW, wll)
    GEMM_OPERAND(XEM_ROW, wr)
    #undef ATL_ROW
    #undef ALL_ROW
    #undef XEM_ROW

    #pragma unroll
    for (int r = 0; r < 4; ++r) {
        if (i0 + r < n) {
            float4 o;
            o.x = fmaxf(acc[r][0], 0.0f); o.y = fmaxf(acc[r][1], 0.0f);
            o.z = fmaxf(acc[r][2], 0.0f); o.w = fmaxf(acc[r][3], 0.0f);
            *(float4*)(out + (size_t)(i0 + r) * 64 + j0) = o;
        }
    }
}

__global__ void __launch_bounds__(256)
epi_title_kernel(const float* __restrict__ agg_lt,
                 const float* __restrict__ title_x,
                 const float* __restrict__ Wl_tl, const float* __restrict__ bl_tl,
                 const float* __restrict__ Wr_tl,
                 float* __restrict__ out, int n)
{
    __shared__ float wl[64][64];
    __shared__ float wr[64][64];
    for (int idx = threadIdx.x; idx < 4096; idx += 256) {
        int k = idx >> 6, j = idx & 63;
        wl[k][j] = Wl_tl[j * 64 + k];
        wr[k][j] = Wr_tl[j * 64 + k];
    }
    __syncthreads();

    int ty = threadIdx.x >> 4, tx = threadIdx.x & 15;
    int i0 = blockIdx.x * 64 + ty * 4;
    int j0 = tx * 4;

    int rr[4] = {min(i0 + 0, n - 1), min(i0 + 1, n - 1),
                 min(i0 + 2, n - 1), min(i0 + 3, n - 1)};

    float4 bias = *(const float4*)(bl_tl + j0);
    float acc[4][4];
    #pragma unroll
    for (int r = 0; r < 4; ++r) {
        acc[r][0] = bias.x; acc[r][1] = bias.y;
        acc[r][2] = bias.z; acc[r][3] = bias.w;
    }

    #define ALT_ROW(r) (agg_lt  + (size_t)rr[r] * 64)
    #define TXX_ROW(r) (title_x + (size_t)rr[r] * 64)
    GEMM_OPERAND(ALT_ROW, wl)
    GEMM_OPERAND(TXX_ROW, wr)
    #undef ALT_ROW
    #undef TXX_ROW

    #pragma unroll
    for (int r = 0; r < 4; ++r) {
        if (i0 + r < n) {
            float4 o;
            o.x = fmaxf(acc[r][0], 0.0f); o.y = fmaxf(acc[r][1], 0.0f);
            o.z = fmaxf(acc[r][2], 0.0f); o.w = fmaxf(acc[r][3], 0.0f);
            *(float4*)(out + (size_t)(i0 + r) * 64 + j0) = o;
        }
    }
}

extern "C" void kernel_launch(void* const* d_in, const int* in_sizes, int n_in,
                              void* d_out, int out_size, void* d_ws, size_t ws_size,
                              hipStream_t stream)
{
    const float* title_x   = (const float*)d_in[0];
    const float* label_emb = (const float*)d_in[1];
    const float* Wl_tl     = (const float*)d_in[2];
    const float* bl_tl     = (const float*)d_in[3];
    const float* Wr_tl     = (const float*)d_in[4];
    const float* Wl_ll     = (const float*)d_in[5];
    const float* bl_ll     = (const float*)d_in[6];
    const float* Wr_ll     = (const float*)d_in[7];
    const int* label_node_id = (const int*)d_in[8];
    const int* tl_src = (const int*)d_in[9];
    const int* tl_dst = (const int*)d_in[10];
    const int* lt_src = (const int*)d_in[11];
    const int* lt_dst = (const int*)d_in[12];
    const int* ll_src = (const int*)d_in[13];
    const int* ll_dst = (const int*)d_in[14];

    const int NT  = in_sizes[0] / 64;
    const int NL  = in_sizes[8];
    const int eTL = in_sizes[9];
    const int eLT = in_sizes[11];
    const int eLL = in_sizes[13];

    // ---- workspace overlay --------------------------------------------------
    size_t szAgL = (size_t)NL * 64 * 4;       // one label agg: 25.6 MB
    size_t szAgT = (size_t)NT * 64 * 4;       // title agg:     51.2 MB
    size_t iNL   = (size_t)NL * 4;
    size_t iNT   = (size_t)NT * 4;
    size_t szBs  = 1024 * 4;                  // block sums (<=1024 blocks)

    size_t regionA = 2 * szAgL + 6 * iNL + ((size_t)eTL + eLL) * 4;  // ~63 MB
    size_t regionB = szAgT + 3 * iNT + (size_t)eLT * 4;              // ~60 MB
    size_t big     = regionA > regionB ? regionA : regionB;
    size_t needed  = big + szBs;

    float* out_label = (float*)d_out;
    float* out_title = out_label + (size_t)NL * 64;

    if (ws_size < needed) {  // diagnosable failure: absmax ~999
        sentinel_kernel<<<(out_size + 255) / 256, 256, 0, stream>>>((float*)d_out, out_size);
        return;
    }

    char* base = (char*)d_ws;
    // phase A layout
    float* agg_tl = (float*)(base);
    float* agg_ll = (float*)(base + szAgL);
    int* cnt_tl = (int*)(base + 2 * szAgL);
    int* cnt_ll = (int*)(base + 2 * szAgL + iNL);
    int* rp_tl  = (int*)(base + 2 * szAgL + 2 * iNL);
    int* rp_ll  = (int*)(base + 2 * szAgL + 3 * iNL);
    int* cur_tl = (int*)(base + 2 * szAgL + 4 * iNL);
    int* cur_ll = (int*)(base + 2 * szAgL + 5 * iNL);
    int* bkt_tl = (int*)(base + 2 * szAgL + 6 * iNL);
    int* bkt_ll = bkt_tl + eTL;
    // phase B layout (overlays A; stream-ordered)
    float* agg_lt = (float*)(base);
    int* cnt_lt = (int*)(base + szAgT);
    int* rp_lt  = (int*)(base + szAgT + iNT);
    int* cur_lt = (int*)(base + szAgT + 2 * iNT);
    int* bkt_lt = (int*)(base + szAgT + 3 * iNT);
    int* bsum   = (int*)(base + big);          // shared by all scans (serial)

    auto eblk = [](int n) { return (n + 255) / 256; };
    auto sblk = [](int n) { return (n + 2047) / 2048; };

    auto scan = [&](const int* cnt, int* rp, int* cur, int n) {
        int nb = sblk(n);
        scan_reduce_kernel<<<nb, 256, 0, stream>>>(cnt, bsum, n);
        scan_bsum_kernel<<<1, 1024, 0, stream>>>(bsum, nb);
        scan_apply_kernel<<<nb, 256, 0, stream>>>(cnt, bsum, rp, cur, n);
    };

    // ---- phase A: label destination ----------------------------------------
    (void)hipMemsetAsync(cnt_tl, 0, 2 * iNL, stream);   // cnt_tl + cnt_ll
    hist_kernel<<<eblk(eTL), 256, 0, stream>>>(tl_dst, cnt_tl, eTL);
    hist_kernel<<<eblk(eLL), 256, 0, stream>>>(ll_dst, cnt_ll, eLL);
    scan(cnt_tl, rp_tl, cur_tl, NL);
    scan(cnt_ll, rp_ll, cur_ll, NL);
    scatter_kernel<<<eblk(eTL), 256, 0, stream>>>(tl_src, tl_dst, nullptr, cur_tl, bkt_tl, eTL);
    scatter_kernel<<<eblk(eLL), 256, 0, stream>>>(ll_src, ll_dst, label_node_id, cur_ll, bkt_ll, eLL);
    gather_mean_kernel<<<(NL + 3) / 4, 256, 0, stream>>>(title_x,   rp_tl, cnt_tl, bkt_tl, agg_tl, NL);
    gather_mean_kernel<<<(NL + 3) / 4, 256, 0, stream>>>(label_emb, rp_ll, cnt_ll, bkt_ll, agg_ll, NL);
    epi_label_kernel<<<(NL + 63) / 64, 256, 0, stream>>>(
        agg_tl, agg_ll, label_emb, label_node_id,
        Wl_tl, bl_tl, Wr_tl, Wl_ll, bl_ll, Wr_ll, out_label, NL);

    // ---- phase B: title destination (stream-ordered reuse) -----------------
    (void)hipMemsetAsync(cnt_lt, 0, iNT, stream);
    hist_kernel<<<eblk(eLT), 256, 0, stream>>>(lt_dst, cnt_lt, eLT);
    scan(cnt_lt, rp_lt, cur_lt, NT);
    scatter_kernel<<<eblk(eLT), 256, 0, stream>>>(lt_src, lt_dst, label_node_id, cur_lt, bkt_lt, eLT);
    gather_mean_kernel<<<(NT + 3) / 4, 256, 0, stream>>>(label_emb, rp_lt, cnt_lt, bkt_lt, agg_lt, NT);
    epi_title_kernel<<<(NT + 63) / 64, 256, 0, stream>>>(
        agg_lt, title_x, Wl_tl, bl_tl, Wr_tl, out_title, NT);
}

// Round 13
// 566.712 us; speedup vs baseline: 9.0704x; 1.6621x over previous
//
#include <hip/hip_runtime.h>
#include <hip/hip_bf16.h>

// GNN_84043920048593: hetero SAGEConv. f32 I/O.
// R10/R11 lesson: random 4B writes cost a 64B line writeback regardless of
// store vs atomic (scatter: 100MB traffic for 6.4MB payload). R12: two-level
// binned CSR build — coarse multisplit with LDS staging (contiguous segment
// writes), then per-bin build where one block owns a ~32KB bucket range.

typedef unsigned int u32;
typedef unsigned char u8;

__global__ void sentinel_kernel(float* out, int n) {
    int i = blockIdx.x * 256 + threadIdx.x;
    if (i < n) out[i] = 999.0f;
}

// ---------- pass 0: coarse bin histogram (LDS-aggregated) -------------------
__global__ void __launch_bounds__(256)
bin_hist_kernel(const int* __restrict__ dst, int* __restrict__ binhist,
                int n, int shift) {
    __shared__ int lh[256];
    int tid = threadIdx.x;
    lh[tid] = 0;
    __syncthreads();
    int base = blockIdx.x * 4096;
    #pragma unroll
    for (int k = 0; k < 16; ++k) {
        int e = base + k * 256 + tid;
        if (e < n) atomicAdd(&lh[dst[e] >> shift], 1);
    }
    __syncthreads();
    if (lh[tid] > 0) atomicAdd(binhist + tid, lh[tid]);
}

// ---------- coarse scan: binhist -> start[0..nbins] (excl), cur=start -------
__global__ void __launch_bounds__(256)
bin_scan_kernel(const int* __restrict__ binhist, int* __restrict__ start,
                int* __restrict__ cur_bin, int nbins) {
    __shared__ int sh[256];
    int t = threadIdx.x;
    int v = (t < nbins) ? binhist[t] : 0;
    sh[t] = v;
    __syncthreads();
    for (int off = 1; off < 256; off <<= 1) {
        int u = (t >= off) ? sh[t - off] : 0;
        __syncthreads();
        sh[t] += u;
        __syncthreads();
    }
    if (t < nbins) { start[t] = sh[t] - v; cur_bin[t] = sh[t] - v; }
    if (t == 255) start[nbins] = sh[255];
}

// ---------- pass 1: block-local multisplit -> staging segments --------------
// stage packed u32 = (dst_low << 18) | src   (src < 2^18, dst_low < 2^10)
__global__ void __launch_bounds__(256)
bin_scatter_kernel(const int* __restrict__ src, const int* __restrict__ dst,
                   const int* __restrict__ remap,
                   int* __restrict__ cur_bin, u32* __restrict__ staging,
                   int n, int shift) {
    __shared__ int lh[256], sc[256], lrp[256], lcur[256], lbase[256];
    __shared__ u32 stage[4096];
    __shared__ u8  sbin[4096];
    int tid = threadIdx.x;
    lh[tid] = 0;
    __syncthreads();
    int base = blockIdx.x * 4096;
    int mybin[16]; u32 mypk[16];
    int dmask = (1 << shift) - 1;
    #pragma unroll
    for (int k = 0; k < 16; ++k) {
        int e = base + k * 256 + tid;
        mybin[k] = -1;
        if (e < n) {
            int d = dst[e];
            int s = src[e];
            if (remap) s = remap[s];
            int b = d >> shift;
            mybin[k] = b;
            mypk[k] = ((u32)(d & dmask) << 18) | (u32)s;
            atomicAdd(&lh[b], 1);
        }
    }
    __syncthreads();
    int v = lh[tid];
    sc[tid] = v;
    __syncthreads();
    for (int off = 1; off < 256; off <<= 1) {
        int u = (tid >= off) ? sc[tid - off] : 0;
        __syncthreads();
        sc[tid] += u;
        __syncthreads();
    }
    lrp[tid] = sc[tid] - v;
    lcur[tid] = sc[tid] - v;
    if (v > 0) lbase[tid] = atomicAdd(&cur_bin[tid], v);
    __syncthreads();
    #pragma unroll
    for (int k = 0; k < 16; ++k) {
        if (mybin[k] >= 0) {
            int p = atomicAdd(&lcur[mybin[k]], 1);
            stage[p] = mypk[k];
            sbin[p] = (u8)mybin[k];
        }
    }
    __syncthreads();
    int cnt_here = min(4096, n - base);
    for (int i = tid; i < cnt_here; i += 256) {
        int b = sbin[i];
        staging[lbase[b] + (i - lrp[b])] = stage[i];
    }
}

// ---------- pass 2: per-bin fine build -> bucket, rp, cnt -------------------
// one block per bin; bin's bucket range (~32KB) is block-exclusive -> L2-hot.
__global__ void __launch_bounds__(256)
bin_build_kernel(const u32* __restrict__ staging, const int* __restrict__ start,
                 int* __restrict__ bucket, int* __restrict__ rp,
                 int* __restrict__ cnt, int shift, int n_dst) {
    __shared__ int fh[1024], frp[1024], fcur[1024], part[256];
    int tid = threadIdx.x;
    int b = blockIdx.x;
    int s0 = start[b], s1 = start[b + 1];
    int m = s1 - s0;
    int nd = 1 << shift;
    int dbase = b << shift;
    for (int j = tid; j < nd; j += 256) fh[j] = 0;
    __syncthreads();
    for (int i = tid; i < m; i += 256)
        atomicAdd(&fh[staging[s0 + i] >> 18], 1);
    __syncthreads();
    // blocked exclusive scan of fh[0..nd)
    int K = nd >> 8;                       // 2 (shift=9) or 4 (shift=10)
    int t0 = tid * K;
    int s = 0;
    for (int k = 0; k < K; ++k) s += fh[t0 + k];
    part[tid] = s;
    __syncthreads();
    for (int off = 1; off < 256; off <<= 1) {
        int u = (tid >= off) ? part[tid - off] : 0;
        __syncthreads();
        part[tid] += u;
        __syncthreads();
    }
    int run = part[tid] - s;
    for (int k = 0; k < K; ++k) {
        frp[t0 + k] = run; fcur[t0 + k] = run;
        run += fh[t0 + k];
    }
    __syncthreads();
    for (int j = tid; j < nd; j += 256) {
        int d = dbase + j;
        if (d < n_dst) { rp[d] = s0 + frp[j]; cnt[d] = fh[j]; }
    }
    for (int i = tid; i < m; i += 256) {
        u32 pk = staging[s0 + i];
        int dl = pk >> 18;
        int p = atomicAdd(&fcur[dl], 1);
        bucket[s0 + p] = (int)(pk & 0x3FFFFu);
    }
}

// ---------- gather-reduce: 4 rows per wave-iteration ------------------------
__global__ void __launch_bounds__(256)
gather_mean_kernel(const float* __restrict__ x,
                   const int* __restrict__ rp,
                   const int* __restrict__ cnt,
                   const int* __restrict__ bucket,
                   float* __restrict__ agg,
                   int n_dst)
{
    int wave = threadIdx.x >> 6, lane = threadIdx.x & 63;
    int i = blockIdx.x * 4 + wave;
    if (i >= n_dst) return;
    int st = rp[i], deg = cnt[i];
    int q = lane >> 4, c = lane & 15;
    float4 acc = make_float4(0.f, 0.f, 0.f, 0.f);
    for (int j = 0; j < deg; j += 4) {
        int idx = j + q;
        int r = bucket[st + min(idx, deg - 1)];
        float m = (idx < deg) ? 1.0f : 0.0f;
        float4 v = ((const float4*)x)[(size_t)r * 16 + c];
        acc.x += m * v.x; acc.y += m * v.y;
        acc.z += m * v.z; acc.w += m * v.w;
    }
    acc.x += __shfl_xor(acc.x, 16); acc.y += __shfl_xor(acc.y, 16);
    acc.z += __shfl_xor(acc.z, 16); acc.w += __shfl_xor(acc.w, 16);
    acc.x += __shfl_xor(acc.x, 32); acc.y += __shfl_xor(acc.y, 32);
    acc.z += __shfl_xor(acc.z, 32); acc.w += __shfl_xor(acc.w, 32);
    if (q == 0) {
        float inv = 1.0f / fmaxf((float)deg, 1.0f);
        ((float4*)agg)[(size_t)i * 16 + c] =
            make_float4(acc.x * inv, acc.y * inv, acc.z * inv, acc.w * inv);
    }
}

// ---------- epilogues: register-tiled GEMM, 4x4 outputs per thread ----------
#define GEMM_OPERAND(AROW_EXPR, WLDS)                                      \
    for (int kb = 0; kb < 64; kb += 4) {                                   \
        float4 a0 = *(const float4*)((AROW_EXPR(0)) + kb);                 \
        float4 a1 = *(const float4*)((AROW_EXPR(1)) + kb);                 \
        float4 a2 = *(const float4*)((AROW_EXPR(2)) + kb);                 \
        float4 a3 = *(const float4*)((AROW_EXPR(3)) + kb);                 \
        _Pragma("unroll")                                                  \
        for (int kk = 0; kk < 4; ++kk) {                                   \
            float4 w = *(const float4*)(&WLDS[kb + kk][j0]);               \
            float av0 = ((const float*)&a0)[kk];                           \
            float av1 = ((const float*)&a1)[kk];                           \
            float av2 = ((const float*)&a2)[kk];                           \
            float av3 = ((const float*)&a3)[kk];                           \
            acc[0][0] += av0 * w.x; acc[0][1] += av0 * w.y;                \
            acc[0][2] += av0 * w.z; acc[0][3] += av0 * w.w;                \
            acc[1][0] += av1 * w.x; acc[1][1] += av1 * w.y;                \
            acc[1][2] += av1 * w.z; acc[1][3] += av1 * w.w;                \
            acc[2][0] += av2 * w.x; acc[2][1] += av2 * w.y;                \
            acc[2][2] += av2 * w.z; acc[2][3] += av2 * w.w;                \
            acc[3][0] += av3 * w.x; acc[3][1] += av3 * w.y;                \
            acc[3][2] += av3 * w.z; acc[3][3] += av3 * w.w;                \
        }                                                                  \
    }

__global__ void __launch_bounds__(256)
epi_label_kernel(const float* __restrict__ agg_tl,
                 const float* __restrict__ agg_ll,
                 const float* __restrict__ xemb,
                 const int* __restrict__ nid,
                 const float* __restrict__ Wl_tl, const float* __restrict__ bl_tl,
                 const float* __restrict__ Wr_tl,
                 const float* __restrict__ Wl_ll, const float* __restrict__ bl_ll,
                 const float* __restrict__ Wr_ll,
                 float* __restrict__ out, int n)
{
    __shared__ float wtl[64][64];
    __shared__ float wll[64][64];
    __shared__ float wr [64][64];
    for (int idx = threadIdx.x; idx < 4096; idx += 256) {
        int k = idx >> 6, j = idx & 63;
        wtl[k][j] = Wl_tl[j * 64 + k];
        wll[k][j] = Wl_ll[j * 64 + k];
        wr [k][j] = Wr_tl[j * 64 + k] + Wr_ll[j * 64 + k];
    }
    __syncthreads();

    int ty = threadIdx.x >> 4, tx = threadIdx.x & 15;
    int i0 = blockIdx.x * 64 + ty * 4;
    int j0 = tx * 4;

    int rr[4] = {min(i0 + 0, n - 1), min(i0 + 1, n - 1),
                 min(i0 + 2, n - 1), min(i0 + 3, n - 1)};
    int nd[4] = {nid[rr[0]], nid[rr[1]], nid[rr[2]], nid[rr[3]]};

    float4 bias;
    bias.x = bl_tl[j0+0] + bl_ll[j0+0];
    bias.y = bl_tl[j0+1] + bl_ll[j0+1];
    bias.z = bl_tl[j0+2] + bl_ll[j0+2];
    bias.w = bl_tl[j0+3] + bl_ll[j0+3];
    float acc[4][4];
    #pragma unroll
    for (int r = 0; r < 4; ++r) {
        acc[r][0] = bias.x; acc[r][1] = bias.y;
        acc[r][2] = bias.z; acc[r][3] = bias.w;
    }

    #define ATL_ROW(r) (agg_tl + (size_t)rr[r] * 64)
    #define ALL_ROW(r) (agg_ll + (size_t)rr[r] * 64)
    #define XEM_ROW(r) (xemb  + (size_t)nd[r] * 64)
    GEMM_OPERAND(ATL_ROW, wtl)
    GEMM_OPERAND(ALL_ROW, wll)
    GEMM_OPERAND(XEM_ROW, wr)
    #undef ATL_ROW
    #undef ALL_ROW
    #undef XEM_ROW

    #pragma unroll
    for (int r = 0; r < 4; ++r) {
        if (i0 + r < n) {
            float4 o;
            o.x = fmaxf(acc[r][0], 0.0f); o.y = fmaxf(acc[r][1], 0.0f);
            o.z = fmaxf(acc[r][2], 0.0f); o.w = fmaxf(acc[r][3], 0.0f);
            *(float4*)(out + (size_t)(i0 + r) * 64 + j0) = o;
        }
    }
}

__global__ void __launch_bounds__(256)
epi_title_kernel(const float* __restrict__ agg_lt,
                 const float* __restrict__ title_x,
                 const float* __restrict__ Wl_tl, const float* __restrict__ bl_tl,
                 const float* __restrict__ Wr_tl,
                 float* __restrict__ out, int n)
{
    __shared__ float wl[64][64];
    __shared__ float wr[64][64];
    for (int idx = threadIdx.x; idx < 4096; idx += 256) {
        int k = idx >> 6, j = idx & 63;
        wl[k][j] = Wl_tl[j * 64 + k];
        wr[k][j] = Wr_tl[j * 64 + k];
    }
    __syncthreads();

    int ty = threadIdx.x >> 4, tx = threadIdx.x & 15;
    int i0 = blockIdx.x * 64 + ty * 4;
    int j0 = tx * 4;

    int rr[4] = {min(i0 + 0, n - 1), min(i0 + 1, n - 1),
                 min(i0 + 2, n - 1), min(i0 + 3, n - 1)};

    float4 bias = *(const float4*)(bl_tl + j0);
    float acc[4][4];
    #pragma unroll
    for (int r = 0; r < 4; ++r) {
        acc[r][0] = bias.x; acc[r][1] = bias.y;
        acc[r][2] = bias.z; acc[r][3] = bias.w;
    }

    #define ALT_ROW(r) (agg_lt  + (size_t)rr[r] * 64)
    #define TXX_ROW(r) (title_x + (size_t)rr[r] * 64)
    GEMM_OPERAND(ALT_ROW, wl)
    GEMM_OPERAND(TXX_ROW, wr)
    #undef ALT_ROW
    #undef TXX_ROW

    #pragma unroll
    for (int r = 0; r < 4; ++r) {
        if (i0 + r < n) {
            float4 o;
            o.x = fmaxf(acc[r][0], 0.0f); o.y = fmaxf(acc[r][1], 0.0f);
            o.z = fmaxf(acc[r][2], 0.0f); o.w = fmaxf(acc[r][3], 0.0f);
            *(float4*)(out + (size_t)(i0 + r) * 64 + j0) = o;
        }
    }
}

extern "C" void kernel_launch(void* const* d_in, const int* in_sizes, int n_in,
                              void* d_out, int out_size, void* d_ws, size_t ws_size,
                              hipStream_t stream)
{
    const float* title_x   = (const float*)d_in[0];
    const float* label_emb = (const float*)d_in[1];
    const float* Wl_tl     = (const float*)d_in[2];
    const float* bl_tl     = (const float*)d_in[3];
    const float* Wr_tl     = (const float*)d_in[4];
    const float* Wl_ll     = (const float*)d_in[5];
    const float* bl_ll     = (const float*)d_in[6];
    const float* Wr_ll     = (const float*)d_in[7];
    const int* label_node_id = (const int*)d_in[8];
    const int* tl_src = (const int*)d_in[9];
    const int* tl_dst = (const int*)d_in[10];
    const int* lt_src = (const int*)d_in[11];
    const int* lt_dst = (const int*)d_in[12];
    const int* ll_src = (const int*)d_in[13];
    const int* ll_dst = (const int*)d_in[14];

    const int NT  = in_sizes[0] / 64;
    const int NL  = in_sizes[8];
    const int eTL = in_sizes[9];
    const int eLT = in_sizes[11];
    const int eLL = in_sizes[13];

    const int SH_L = 9,  NB_L = (NL + 511) >> 9;     // label bins (<=256)
    const int SH_T = 10, NB_T = (NT + 1023) >> 10;   // title bins (<=256)

    // ---- workspace overlay --------------------------------------------------
    size_t szAgL = (size_t)NL * 64 * 4;       // 25.6 MB
    size_t szAgT = (size_t)NT * 64 * 4;       // 51.2 MB
    size_t iNL   = (size_t)NL * 4;
    size_t iNT   = (size_t)NT * 4;

    // phase A: agg_tl | agg_ll(+staging overlay) | rp/cnt x2 | bkt_tl | bkt_ll
    size_t regionA = 2 * szAgL + 4 * iNL + ((size_t)eTL + eLL) * 4;  // ~62.4MB
    // phase B: agg_lt(+staging overlay) | rp/cnt | bkt_lt
    size_t regionB = szAgT + 2 * iNT + (size_t)eLT * 4;              // ~59.2MB
    size_t big     = regionA > regionB ? regionA : regionB;
    size_t szSmall = (256 + 257 + 256) * 4;   // binhist, start, cur_bin
    size_t needed  = big + szSmall;

    float* out_label = (float*)d_out;
    float* out_title = out_label + (size_t)NL * 64;

    if (ws_size < needed) {  // diagnosable failure: absmax ~999
        sentinel_kernel<<<(out_size + 255) / 256, 256, 0, stream>>>((float*)d_out, out_size);
        return;
    }

    char* base = (char*)d_ws;
    // phase A layout
    float* agg_tl  = (float*)(base);
    float* agg_ll  = (float*)(base + szAgL);
    u32*   stagA   = (u32*)  (base + szAgL);            // overlays agg_ll
    int* rp_tl  = (int*)(base + 2 * szAgL);
    int* cnt_tl = (int*)(base + 2 * szAgL + iNL);
    int* rp_ll  = (int*)(base + 2 * szAgL + 2 * iNL);
    int* cnt_ll = (int*)(base + 2 * szAgL + 3 * iNL);
    int* bkt_tl = (int*)(base + 2 * szAgL + 4 * iNL);
    int* bkt_ll = bkt_tl + eTL;
    // phase B layout (overlays A; stream-ordered)
    float* agg_lt = (float*)(base);
    u32*   stagB  = (u32*)(base);                        // overlays agg_lt
    int* rp_lt  = (int*)(base + szAgT);
    int* cnt_lt = (int*)(base + szAgT + iNT);
    int* bkt_lt = (int*)(base + szAgT + 2 * iNT);
    // small tail arrays (reused serially by every CSR build)
    int* binhist = (int*)(base + big);
    int* startb  = binhist + 256;
    int* curbin  = startb + 257;

    auto nchunk = [](int n) { return (n + 4095) / 4096; };

    // build CSR for one edge type (serial use of binhist/startb/curbin)
    auto build_csr = [&](const int* esrc, const int* edst, const int* remap,
                         u32* staging, int* bucket, int* rp, int* cnt,
                         int n_edges, int n_dst, int shift, int nbins) {
        (void)hipMemsetAsync(binhist, 0, nbins * 4, stream);
        bin_hist_kernel<<<nchunk(n_edges), 256, 0, stream>>>(edst, binhist, n_edges, shift);
        bin_scan_kernel<<<1, 256, 0, stream>>>(binhist, startb, curbin, nbins);
        bin_scatter_kernel<<<nchunk(n_edges), 256, 0, stream>>>(
            esrc, edst, remap, curbin, staging, n_edges, shift);
        bin_build_kernel<<<nbins, 256, 0, stream>>>(
            staging, startb, bucket, rp, cnt, shift, n_dst);
    };

    // ---- phase A: label destination ----------------------------------------
    build_csr(tl_src, tl_dst, nullptr,       stagA, bkt_tl, rp_tl, cnt_tl, eTL, NL, SH_L, NB_L);
    build_csr(ll_src, ll_dst, label_node_id, stagA, bkt_ll, rp_ll, cnt_ll, eLL, NL, SH_L, NB_L);
    gather_mean_kernel<<<(NL + 3) / 4, 256, 0, stream>>>(title_x,   rp_tl, cnt_tl, bkt_tl, agg_tl, NL);
    gather_mean_kernel<<<(NL + 3) / 4, 256, 0, stream>>>(label_emb, rp_ll, cnt_ll, bkt_ll, agg_ll, NL);
    epi_label_kernel<<<(NL + 63) / 64, 256, 0, stream>>>(
        agg_tl, agg_ll, label_emb, label_node_id,
        Wl_tl, bl_tl, Wr_tl, Wl_ll, bl_ll, Wr_ll, out_label, NL);

    // ---- phase B: title destination (stream-ordered reuse) -----------------
    build_csr(lt_src, lt_dst, label_node_id, stagB, bkt_lt, rp_lt, cnt_lt, eLT, NT, SH_T, NB_T);
    gather_mean_kernel<<<(NT + 3) / 4, 256, 0, stream>>>(label_emb, rp_lt, cnt_lt, bkt_lt, agg_lt, NT);
    epi_title_kernel<<<(NT + 63) / 64, 256, 0, stream>>>(
        agg_lt, title_x, Wl_tl, bl_tl, Wr_tl, out_title, NT);
}

// Round 14
// 539.641 us; speedup vs baseline: 9.5254x; 1.0502x over previous
//
#include <hip/hip_runtime.h>
#include <hip/hip_bf16.h>

// GNN_84043920048593: hetero SAGEConv. f32 I/O.
// R13: 567us; epi_label 118us @ 27% occ / 25% VALUBusy — LDS-bound (48KB LDS
// caps 3 blk/CU; only 16 FMA per ds_read_b128). R14: sequential-W phases
// (16KB LDS, one W at a time) + 8x4 per-thread tile (32 FMA per w-read),
// __launch_bounds__(256,4) to pin VGPR<=128 -> 16 waves/CU.

typedef unsigned int u32;
typedef unsigned char u8;

__global__ void sentinel_kernel(float* out, int n) {
    int i = blockIdx.x * 256 + threadIdx.x;
    if (i < n) out[i] = 999.0f;
}

// ---------- pass 0: coarse bin histogram (LDS-aggregated) -------------------
__global__ void __launch_bounds__(256)
bin_hist_kernel(const int* __restrict__ dst, int* __restrict__ binhist,
                int n, int shift) {
    __shared__ int lh[256];
    int tid = threadIdx.x;
    lh[tid] = 0;
    __syncthreads();
    int base = blockIdx.x * 4096;
    #pragma unroll
    for (int k = 0; k < 16; ++k) {
        int e = base + k * 256 + tid;
        if (e < n) atomicAdd(&lh[dst[e] >> shift], 1);
    }
    __syncthreads();
    if (lh[tid] > 0) atomicAdd(binhist + tid, lh[tid]);
}

// ---------- coarse scan: binhist -> start[0..nbins] (excl), cur=start -------
__global__ void __launch_bounds__(256)
bin_scan_kernel(const int* __restrict__ binhist, int* __restrict__ start,
                int* __restrict__ cur_bin, int nbins) {
    __shared__ int sh[256];
    int t = threadIdx.x;
    int v = (t < nbins) ? binhist[t] : 0;
    sh[t] = v;
    __syncthreads();
    for (int off = 1; off < 256; off <<= 1) {
        int u = (t >= off) ? sh[t - off] : 0;
        __syncthreads();
        sh[t] += u;
        __syncthreads();
    }
    if (t < nbins) { start[t] = sh[t] - v; cur_bin[t] = sh[t] - v; }
    if (t == 255) start[nbins] = sh[255];
}

// ---------- pass 1: block-local multisplit -> staging segments --------------
// stage packed u32 = (dst_low << 18) | src   (src < 2^18, dst_low < 2^10)
__global__ void __launch_bounds__(256)
bin_scatter_kernel(const int* __restrict__ src, const int* __restrict__ dst,
                   const int* __restrict__ remap,
                   int* __restrict__ cur_bin, u32* __restrict__ staging,
                   int n, int shift) {
    __shared__ int lh[256], sc[256], lrp[256], lcur[256], lbase[256];
    __shared__ u32 stage[4096];
    __shared__ u8  sbin[4096];
    int tid = threadIdx.x;
    lh[tid] = 0;
    __syncthreads();
    int base = blockIdx.x * 4096;
    int mybin[16]; u32 mypk[16];
    int dmask = (1 << shift) - 1;
    #pragma unroll
    for (int k = 0; k < 16; ++k) {
        int e = base + k * 256 + tid;
        mybin[k] = -1;
        if (e < n) {
            int d = dst[e];
            int s = src[e];
            if (remap) s = remap[s];
            int b = d >> shift;
            mybin[k] = b;
            mypk[k] = ((u32)(d & dmask) << 18) | (u32)s;
            atomicAdd(&lh[b], 1);
        }
    }
    __syncthreads();
    int v = lh[tid];
    sc[tid] = v;
    __syncthreads();
    for (int off = 1; off < 256; off <<= 1) {
        int u = (tid >= off) ? sc[tid - off] : 0;
        __syncthreads();
        sc[tid] += u;
        __syncthreads();
    }
    lrp[tid] = sc[tid] - v;
    lcur[tid] = sc[tid] - v;
    if (v > 0) lbase[tid] = atomicAdd(&cur_bin[tid], v);
    __syncthreads();
    #pragma unroll
    for (int k = 0; k < 16; ++k) {
        if (mybin[k] >= 0) {
            int p = atomicAdd(&lcur[mybin[k]], 1);
            stage[p] = mypk[k];
            sbin[p] = (u8)mybin[k];
        }
    }
    __syncthreads();
    int cnt_here = min(4096, n - base);
    for (int i = tid; i < cnt_here; i += 256) {
        int b = sbin[i];
        staging[lbase[b] + (i - lrp[b])] = stage[i];
    }
}

// ---------- pass 2: per-bin fine build -> bucket, rp, cnt -------------------
__global__ void __launch_bounds__(256)
bin_build_kernel(const u32* __restrict__ staging, const int* __restrict__ start,
                 int* __restrict__ bucket, int* __restrict__ rp,
                 int* __restrict__ cnt, int shift, int n_dst) {
    __shared__ int fh[1024], frp[1024], fcur[1024], part[256];
    int tid = threadIdx.x;
    int b = blockIdx.x;
    int s0 = start[b], s1 = start[b + 1];
    int m = s1 - s0;
    int nd = 1 << shift;
    int dbase = b << shift;
    for (int j = tid; j < nd; j += 256) fh[j] = 0;
    __syncthreads();
    for (int i = tid; i < m; i += 256)
        atomicAdd(&fh[staging[s0 + i] >> 18], 1);
    __syncthreads();
    int K = nd >> 8;
    int t0 = tid * K;
    int s = 0;
    for (int k = 0; k < K; ++k) s += fh[t0 + k];
    part[tid] = s;
    __syncthreads();
    for (int off = 1; off < 256; off <<= 1) {
        int u = (tid >= off) ? part[tid - off] : 0;
        __syncthreads();
        part[tid] += u;
        __syncthreads();
    }
    int run = part[tid] - s;
    for (int k = 0; k < K; ++k) {
        frp[t0 + k] = run; fcur[t0 + k] = run;
        run += fh[t0 + k];
    }
    __syncthreads();
    for (int j = tid; j < nd; j += 256) {
        int d = dbase + j;
        if (d < n_dst) { rp[d] = s0 + frp[j]; cnt[d] = fh[j]; }
    }
    for (int i = tid; i < m; i += 256) {
        u32 pk = staging[s0 + i];
        int dl = pk >> 18;
        int p = atomicAdd(&fcur[dl], 1);
        bucket[s0 + p] = (int)(pk & 0x3FFFFu);
    }
}

// ---------- gather-reduce: 4 rows per wave-iteration ------------------------
__global__ void __launch_bounds__(256)
gather_mean_kernel(const float* __restrict__ x,
                   const int* __restrict__ rp,
                   const int* __restrict__ cnt,
                   const int* __restrict__ bucket,
                   float* __restrict__ agg,
                   int n_dst)
{
    int wave = threadIdx.x >> 6, lane = threadIdx.x & 63;
    int i = blockIdx.x * 4 + wave;
    if (i >= n_dst) return;
    int st = rp[i], deg = cnt[i];
    int q = lane >> 4, c = lane & 15;
    float4 acc = make_float4(0.f, 0.f, 0.f, 0.f);
    for (int j = 0; j < deg; j += 4) {
        int idx = j + q;
        int r = bucket[st + min(idx, deg - 1)];
        float m = (idx < deg) ? 1.0f : 0.0f;
        float4 v = ((const float4*)x)[(size_t)r * 16 + c];
        acc.x += m * v.x; acc.y += m * v.y;
        acc.z += m * v.z; acc.w += m * v.w;
    }
    acc.x += __shfl_xor(acc.x, 16); acc.y += __shfl_xor(acc.y, 16);
    acc.z += __shfl_xor(acc.z, 16); acc.w += __shfl_xor(acc.w, 16);
    acc.x += __shfl_xor(acc.x, 32); acc.y += __shfl_xor(acc.y, 32);
    acc.z += __shfl_xor(acc.z, 32); acc.w += __shfl_xor(acc.w, 32);
    if (q == 0) {
        float inv = 1.0f / fmaxf((float)deg, 1.0f);
        ((float4*)agg)[(size_t)i * 16 + c] =
            make_float4(acc.x * inv, acc.y * inv, acc.z * inv, acc.w * inv);
    }
}

// ---------- epilogues: sequential-W phases, 8x4 per-thread tile -------------
// Block = 128 rows x 64 cols, 256 threads; thread (ty,tx) owns rows
// i0..i0+7, cols j0..j0+3. One 16KB LDS W buffer reused per operand phase.
// Per kb: 8 global float4 (A) + 4 ds_read_b128 (W^T) feed 128 FMAs.

#define GEMM_OPERAND8(AROW, WLDS)                                           \
    for (int kb = 0; kb < 64; kb += 4) {                                    \
        float4 a[8];                                                        \
        _Pragma("unroll")                                                   \
        for (int r = 0; r < 8; ++r) a[r] = *(const float4*)((AROW(r)) + kb);\
        _Pragma("unroll")                                                   \
        for (int kk = 0; kk < 4; ++kk) {                                    \
            float4 w = *(const float4*)(&WLDS[kb + kk][j0]);                \
            _Pragma("unroll")                                               \
            for (int r = 0; r < 8; ++r) {                                   \
                float av = ((const float*)&a[r])[kk];                       \
                acc[r][0] += av * w.x; acc[r][1] += av * w.y;               \
                acc[r][2] += av * w.z; acc[r][3] += av * w.w;               \
            }                                                               \
        }                                                                   \
    }

// load W^T (or sum of two W^T) into wbuf
#define LOAD_W1(Wp)                                                         \
    for (int idx = threadIdx.x; idx < 4096; idx += 256) {                   \
        int k = idx >> 6, j = idx & 63;                                     \
        wbuf[k][j] = (Wp)[j * 64 + k];                                      \
    }
#define LOAD_W2(Wp, Wq)                                                     \
    for (int idx = threadIdx.x; idx < 4096; idx += 256) {                   \
        int k = idx >> 6, j = idx & 63;                                     \
        wbuf[k][j] = (Wp)[j * 64 + k] + (Wq)[j * 64 + k];                   \
    }

__global__ void __launch_bounds__(256, 4)
epi_label_kernel(const float* __restrict__ agg_tl,
                 const float* __restrict__ agg_ll,
                 const float* __restrict__ xemb,
                 const int* __restrict__ nid,
                 const float* __restrict__ Wl_tl, const float* __restrict__ bl_tl,
                 const float* __restrict__ Wr_tl,
                 const float* __restrict__ Wl_ll, const float* __restrict__ bl_ll,
                 const float* __restrict__ Wr_ll,
                 float* __restrict__ out, int n)
{
    __shared__ float wbuf[64][64];   // 16 KB, reused per phase

    int ty = threadIdx.x >> 4, tx = threadIdx.x & 15;
    int i0 = blockIdx.x * 128 + ty * 8;
    int j0 = tx * 4;

    int rr[8], nd[8];
    #pragma unroll
    for (int r = 0; r < 8; ++r) rr[r] = min(i0 + r, n - 1);
    #pragma unroll
    for (int r = 0; r < 8; ++r) nd[r] = nid[rr[r]];

    float4 bias;
    bias.x = bl_tl[j0+0] + bl_ll[j0+0];
    bias.y = bl_tl[j0+1] + bl_ll[j0+1];
    bias.z = bl_tl[j0+2] + bl_ll[j0+2];
    bias.w = bl_tl[j0+3] + bl_ll[j0+3];
    float acc[8][4];
    #pragma unroll
    for (int r = 0; r < 8; ++r) {
        acc[r][0] = bias.x; acc[r][1] = bias.y;
        acc[r][2] = bias.z; acc[r][3] = bias.w;
    }

    // phase 0: Wl_tl^T * agg_tl
    LOAD_W1(Wl_tl)
    __syncthreads();
    #define A0(r) (agg_tl + (size_t)rr[r] * 64)
    GEMM_OPERAND8(A0, wbuf)
    #undef A0
    __syncthreads();

    // phase 1: Wl_ll^T * agg_ll
    LOAD_W1(Wl_ll)
    __syncthreads();
    #define A1(r) (agg_ll + (size_t)rr[r] * 64)
    GEMM_OPERAND8(A1, wbuf)
    #undef A1
    __syncthreads();

    // phase 2: (Wr_tl + Wr_ll)^T * x_label
    LOAD_W2(Wr_tl, Wr_ll)
    __syncthreads();
    #define A2(r) (xemb + (size_t)nd[r] * 64)
    GEMM_OPERAND8(A2, wbuf)
    #undef A2

    #pragma unroll
    for (int r = 0; r < 8; ++r) {
        if (i0 + r < n) {
            float4 o;
            o.x = fmaxf(acc[r][0], 0.0f); o.y = fmaxf(acc[r][1], 0.0f);
            o.z = fmaxf(acc[r][2], 0.0f); o.w = fmaxf(acc[r][3], 0.0f);
            *(float4*)(out + (size_t)(i0 + r) * 64 + j0) = o;
        }
    }
}

__global__ void __launch_bounds__(256, 4)
epi_title_kernel(const float* __restrict__ agg_lt,
                 const float* __restrict__ title_x,
                 const float* __restrict__ Wl_tl, const float* __restrict__ bl_tl,
                 const float* __restrict__ Wr_tl,
                 float* __restrict__ out, int n)
{
    __shared__ float wbuf[64][64];

    int ty = threadIdx.x >> 4, tx = threadIdx.x & 15;
    int i0 = blockIdx.x * 128 + ty * 8;
    int j0 = tx * 4;

    int rr[8];
    #pragma unroll
    for (int r = 0; r < 8; ++r) rr[r] = min(i0 + r, n - 1);

    float4 bias = *(const float4*)(bl_tl + j0);
    float acc[8][4];
    #pragma unroll
    for (int r = 0; r < 8; ++r) {
        acc[r][0] = bias.x; acc[r][1] = bias.y;
        acc[r][2] = bias.z; acc[r][3] = bias.w;
    }

    // phase 0: Wl_tl^T * agg_lt
    LOAD_W1(Wl_tl)
    __syncthreads();
    #define A0(r) (agg_lt + (size_t)rr[r] * 64)
    GEMM_OPERAND8(A0, wbuf)
    #undef A0
    __syncthreads();

    // phase 1: Wr_tl^T * title_x
    LOAD_W1(Wr_tl)
    __syncthreads();
    #define A1(r) (title_x + (size_t)rr[r] * 64)
    GEMM_OPERAND8(A1, wbuf)
    #undef A1

    #pragma unroll
    for (int r = 0; r < 8; ++r) {
        if (i0 + r < n) {
            float4 o;
            o.x = fmaxf(acc[r][0], 0.0f); o.y = fmaxf(acc[r][1], 0.0f);
            o.z = fmaxf(acc[r][2], 0.0f); o.w = fmaxf(acc[r][3], 0.0f);
            *(float4*)(out + (size_t)(i0 + r) * 64 + j0) = o;
        }
    }
}

extern "C" void kernel_launch(void* const* d_in, const int* in_sizes, int n_in,
                              void* d_out, int out_size, void* d_ws, size_t ws_size,
                              hipStream_t stream)
{
    const float* title_x   = (const float*)d_in[0];
    const float* label_emb = (const float*)d_in[1];
    const float* Wl_tl     = (const float*)d_in[2];
    const float* bl_tl     = (const float*)d_in[3];
    const float* Wr_tl     = (const float*)d_in[4];
    const float* Wl_ll     = (const float*)d_in[5];
    const float* bl_ll     = (const float*)d_in[6];
    const float* Wr_ll     = (const float*)d_in[7];
    const int* label_node_id = (const int*)d_in[8];
    const int* tl_src = (const int*)d_in[9];
    const int* tl_dst = (const int*)d_in[10];
    const int* lt_src = (const int*)d_in[11];
    const int* lt_dst = (const int*)d_in[12];
    const int* ll_src = (const int*)d_in[13];
    const int* ll_dst = (const int*)d_in[14];

    const int NT  = in_sizes[0] / 64;
    const int NL  = in_sizes[8];
    const int eTL = in_sizes[9];
    const int eLT = in_sizes[11];
    const int eLL = in_sizes[13];

    const int SH_L = 9,  NB_L = (NL + 511) >> 9;     // label bins (<=256)
    const int SH_T = 10, NB_T = (NT + 1023) >> 10;   // title bins (<=256)

    // ---- workspace overlay --------------------------------------------------
    size_t szAgL = (size_t)NL * 64 * 4;       // 25.6 MB
    size_t szAgT = (size_t)NT * 64 * 4;       // 51.2 MB
    size_t iNL   = (size_t)NL * 4;
    size_t iNT   = (size_t)NT * 4;

    size_t regionA = 2 * szAgL + 4 * iNL + ((size_t)eTL + eLL) * 4;  // ~62.4MB
    size_t regionB = szAgT + 2 * iNT + (size_t)eLT * 4;              // ~59.2MB
    size_t big     = regionA > regionB ? regionA : regionB;
    size_t szSmall = (256 + 257 + 256) * 4;   // binhist, start, cur_bin
    size_t needed  = big + szSmall;

    float* out_label = (float*)d_out;
    float* out_title = out_label + (size_t)NL * 64;

    if (ws_size < needed) {  // diagnosable failure: absmax ~999
        sentinel_kernel<<<(out_size + 255) / 256, 256, 0, stream>>>((float*)d_out, out_size);
        return;
    }

    char* base = (char*)d_ws;
    // phase A layout
    float* agg_tl  = (float*)(base);
    float* agg_ll  = (float*)(base + szAgL);
    u32*   stagA   = (u32*)  (base + szAgL);            // overlays agg_ll
    int* rp_tl  = (int*)(base + 2 * szAgL);
    int* cnt_tl = (int*)(base + 2 * szAgL + iNL);
    int* rp_ll  = (int*)(base + 2 * szAgL + 2 * iNL);
    int* cnt_ll = (int*)(base + 2 * szAgL + 3 * iNL);
    int* bkt_tl = (int*)(base + 2 * szAgL + 4 * iNL);
    int* bkt_ll = bkt_tl + eTL;
    // phase B layout (overlays A; stream-ordered)
    float* agg_lt = (float*)(base);
    u32*   stagB  = (u32*)(base);                        // overlays agg_lt
    int* rp_lt  = (int*)(base + szAgT);
    int* cnt_lt = (int*)(base + szAgT + iNT);
    int* bkt_lt = (int*)(base + szAgT + 2 * iNT);
    int* binhist = (int*)(base + big);
    int* startb  = binhist + 256;
    int* curbin  = startb + 257;

    auto nchunk = [](int n) { return (n + 4095) / 4096; };

    auto build_csr = [&](const int* esrc, const int* edst, const int* remap,
                         u32* staging, int* bucket, int* rp, int* cnt,
                         int n_edges, int n_dst, int shift, int nbins) {
        (void)hipMemsetAsync(binhist, 0, nbins * 4, stream);
        bin_hist_kernel<<<nchunk(n_edges), 256, 0, stream>>>(edst, binhist, n_edges, shift);
        bin_scan_kernel<<<1, 256, 0, stream>>>(binhist, startb, curbin, nbins);
        bin_scatter_kernel<<<nchunk(n_edges), 256, 0, stream>>>(
            esrc, edst, remap, curbin, staging, n_edges, shift);
        bin_build_kernel<<<nbins, 256, 0, stream>>>(
            staging, startb, bucket, rp, cnt, shift, n_dst);
    };

    // ---- phase A: label destination ----------------------------------------
    build_csr(tl_src, tl_dst, nullptr,       stagA, bkt_tl, rp_tl, cnt_tl, eTL, NL, SH_L, NB_L);
    build_csr(ll_src, ll_dst, label_node_id, stagA, bkt_ll, rp_ll, cnt_ll, eLL, NL, SH_L, NB_L);
    gather_mean_kernel<<<(NL + 3) / 4, 256, 0, stream>>>(title_x,   rp_tl, cnt_tl, bkt_tl, agg_tl, NL);
    gather_mean_kernel<<<(NL + 3) / 4, 256, 0, stream>>>(label_emb, rp_ll, cnt_ll, bkt_ll, agg_ll, NL);
    epi_label_kernel<<<(NL + 127) / 128, 256, 0, stream>>>(
        agg_tl, agg_ll, label_emb, label_node_id,
        Wl_tl, bl_tl, Wr_tl, Wl_ll, bl_ll, Wr_ll, out_label, NL);

    // ---- phase B: title destination (stream-ordered reuse) -----------------
    build_csr(lt_src, lt_dst, label_node_id, stagB, bkt_lt, rp_lt, cnt_lt, eLT, NT, SH_T, NB_T);
    gather_mean_kernel<<<(NT + 3) / 4, 256, 0, stream>>>(label_emb, rp_lt, cnt_lt, bkt_lt, agg_lt, NT);
    epi_title_kernel<<<(NT + 127) / 128, 256, 0, stream>>>(
        agg_lt, title_x, Wl_tl, bl_tl, Wr_tl, out_title, NT);
}